// Round 11
// baseline (404.838 us; speedup 1.0000x reference)
//
#include <hip/hip_runtime.h>

#define Sq 2048
#define Dq 64
#define NH 64                    // B*H heads
#define KVBLK 64                 // KV rows per iteration
#define NKVIT (Sq / KVBLK)       // 32
#define PT_STRIDE 72             // P lds row stride (legacy kernels only)

// ---- pre kernel geometry: 4 waves x 32 q-rows = 128 q-rows per block ----
#define QBLK_P 128
#define NQB_P (Sq / QBLK_P)      // 16
#define NBLK_P (NH * NQB_P)      // 1024 blocks (8-XCD bijective)

// ---- legacy geometry (fused fallback + bf16 path) ----
#define QBLK 64
#define NQB (Sq / QBLK)          // 32
#define NBLK (NH * NQB)          // 2048

#define TILE_ELEMS 4096          // 64x64 bf16 per tile image
#define IMG_TILES (NH * NKVIT)   // 2048 tiles per image
#define IMG_BYTES ((size_t)IMG_TILES * TILE_ELEMS * 2)   // 16,777,216 B
#define WS_IMG_OFF 4096
#define WS_NEEDED (WS_IMG_OFF + 2 * IMG_BYTES)           // ~33.6 MB (K + Vt images)

#define QK_SCALE (0.125f * 1.44269504088896f)  // 1/sqrt(D) * log2(e)
#define DEFER_THR 8.0f                          // T13: P bounded by 2^8

typedef __attribute__((ext_vector_type(8))) short bf16x8;   // 8 bf16 = 4 VGPR
typedef __attribute__((ext_vector_type(4))) float f32x4;    // MFMA acc

// ---------- bf16 helpers ----------
__device__ __forceinline__ float bflo(unsigned int u) {
    union { unsigned int i; float f; } x; x.i = u << 16; return x.f;
}
__device__ __forceinline__ unsigned int f2bf(float f) {
    union { float f; unsigned int i; } x; x.f = f;
    return (x.i + 0x7fffu + ((x.i >> 16) & 1u)) >> 16;   // RNE
}
// packed f32x2 -> bf16x2 (RNE), single VALU op
__device__ __forceinline__ unsigned int cvtpk(float lo, float hi) {
    unsigned int r;
    asm("v_cvt_pk_bf16_f32 %0, %1, %2" : "=v"(r) : "v"(lo), "v"(hi));
    return r;
}

// ---------- dtype detector (deterministic; measured flag=0 on this data) ----------
__global__ void detect_dtype(const unsigned int* __restrict__ Q,
                             int* __restrict__ flag) {
    unsigned int u = Q[threadIdx.x];
    float a = fabsf(bflo(u));
    bool sane = (a >= 9.3e-10f) && (a <= 64.0f);
    unsigned long long b = __ballot(sane);
    if (threadIdx.x == 0) *flag = (__builtin_popcountll(b) >= 48) ? 1 : 0;
}

// ---------- async global->LDS, 16B per lane ----------
__device__ __forceinline__ void gload_lds16(const unsigned short* g, unsigned short* l) {
    __builtin_amdgcn_global_load_lds(
        (const __attribute__((address_space(1))) void*)g,
        (__attribute__((address_space(3))) void*)l, 16, 0, 0);
}

// Vt (= V^T [d][kv]) element index with XOR swizzle (write & read use the same map).
__device__ __forceinline__ int vt_swz(int d, int kv) {
    return (d * KVBLK + kv) ^ ((((d & 7) ^ ((d >> 3) & 7))) << 3);
}

// =====================================================================
// Pre-pass: K -> single RNE bf16 image (swizzled rows), V -> V^T bf16.
// One block per 64x64 tile. ~33.6 MB workspace.
// =====================================================================
__global__ __launch_bounds__(256) void convert_kv(
    const float* __restrict__ K, const float* __restrict__ V,
    unsigned short* __restrict__ img, const int* __restrict__ flag)
{
    if (*flag) return;
    __shared__ __align__(16) unsigned short VtL[TILE_ELEMS];

    const int tile = (int)blockIdx.x;
    const int tid  = threadIdx.x;
    const size_t gbase = (size_t)tile * (KVBLK * Dq);

    unsigned short* kim = img + (size_t)tile * TILE_ELEMS;
    unsigned short* vtg = img + (size_t)(IMG_TILES + tile) * TILE_ELEMS;

    const float4* kt4 = (const float4*)(K + gbase);
    const float4* vt4 = (const float4*)(V + gbase);

    #pragma unroll
    for (int c = 0; c < 4; ++c) {
        const int r  = (c * 256 + tid) >> 4;     // row 0..63
        const int c0 = (tid & 15) * 4;           // col base
        {
            float4 u4 = kt4[c * 256 + tid];
            unsigned int p0 = f2bf(u4.x) | (f2bf(u4.y) << 16);   // RNE bf16
            unsigned int p1 = f2bf(u4.z) | (f2bf(u4.w) << 16);
            const int sw = c0 ^ ((r & 7) << 3);
            *(uint2*)(kim + r * 64 + sw) = make_uint2(p0, p1);
        }
        {
            float4 u4 = vt4[c * 256 + tid];
            float xs[4] = {u4.x, u4.y, u4.z, u4.w};
            #pragma unroll
            for (int e = 0; e < 4; ++e)
                VtL[vt_swz(c0 + e, r)] = (unsigned short)f2bf(xs[e]);
        }
    }
    __syncthreads();
    #pragma unroll
    for (int c = 0; c < 2; ++c)
        *(uint4*)(vtg + (c * 256 + tid) * 8) = *(const uint4*)(VtL + (c * 256 + tid) * 8);
}

// ---- softmax common-path (shfl-free defer-max; full reduce only on grow) ----
#define SOFTMAX_BODY(SACC, MR, OA, LA)                                          \
{                                                                               \
    float rmax[4];                                                              \
    _Pragma("unroll")                                                           \
    for (int r = 0; r < 4; ++r)                                                 \
        rmax[r] = fmaxf(fmaxf(SACC[0][r], SACC[1][r]),                          \
                        fmaxf(SACC[2][r], SACC[3][r]));                         \
    bool grow = (rmax[0] > MR[0] + DEFER_THR) | (rmax[1] > MR[1] + DEFER_THR)   \
              | (rmax[2] > MR[2] + DEFER_THR) | (rmax[3] > MR[3] + DEFER_THR);  \
    if (__any(grow)) {                                                          \
        f32x4 av;                                                               \
        _Pragma("unroll")                                                       \
        for (int r = 0; r < 4; ++r) {                                           \
            float t = rmax[r];                                                  \
            _Pragma("unroll")                                                   \
            for (int msk = 1; msk <= 8; msk <<= 1)                              \
                t = fmaxf(t, __shfl_xor(t, msk, 64));                           \
            float mnew = fmaxf(MR[r], t);                                       \
            av[r] = exp2f(MR[r] - mnew);                                        \
            MR[r] = mnew;                                                       \
        }                                                                       \
        _Pragma("unroll")                                                       \
        for (int dt = 0; dt < 4; ++dt) OA[dt] *= av;                            \
        LA *= av;                                                               \
    }                                                                           \
    _Pragma("unroll")                                                           \
    for (int nt = 0; nt < 4; ++nt) {                                            \
        _Pragma("unroll")                                                       \
        for (int r = 0; r < 4; ++r)                                             \
            SACC[nt][r] = exp2f(SACC[nt][r] - MR[r]);                           \
    }                                                                           \
}

// =====================================================================
// Main fp32-input MFMA flash attention: 4 waves x 32 q-rows, single
// bf16 K image (Q hi/lo split: S = Qh K + Ql K), double-buffered
// staging, XOR-swizzled P buffer at stride 64 -> LDS = 40960 B exactly
// -> 4 blocks/CU (16 waves/CU). cvtpk P-writes, setprio.
// =====================================================================
__global__ __launch_bounds__(256, 4) void fa_mfma_f32_pre(
    const float* __restrict__ Q, const unsigned short* __restrict__ img,
    float* __restrict__ O, const int* __restrict__ flag)
{
    if (*flag) return;

    __shared__ __align__(16) unsigned short Kt[2][TILE_ELEMS];   // 16 KiB
    __shared__ __align__(16) unsigned short Vt[2][TILE_ELEMS];   // 16 KiB
    __shared__ __align__(16) unsigned short Pl[4][16 * 64];      // 8 KiB, XOR-swizzled

    const int tid  = threadIdx.x;
    const int lane = tid & 63;
    const int w    = tid >> 6;       // wave 0..3
    const int l15  = lane & 15;
    const int lg   = lane >> 4;

    // XCD-aware bijective swizzle: 1024 blocks = 8 XCDs x 128
    const int bid  = (int)blockIdx.x;
    const int blk  = (bid & 7) * (NBLK_P / 8) + (bid >> 3);
    const int head = blk >> 4;               // 16 q-blocks per head
    const int q0   = (blk & 15) * QBLK_P;
    const size_t hb = (size_t)head * (Sq * Dq);

    // ---- Q fragments: 2 subtiles (m), scaled by 1/8*log2e, hi/lo split ----
    bf16x8 qh[2][2], ql[2][2];   // [m][s]
    #pragma unroll
    for (int m = 0; m < 2; ++m) {
        const float4* qv = (const float4*)(Q + hb
            + (size_t)(q0 + w * 32 + m * 16 + l15) * Dq + lg * 8);
        #pragma unroll
        for (int s = 0; s < 2; ++s) {
            float xs[8];
            #pragma unroll
            for (int j4 = 0; j4 < 2; ++j4) {
                float4 u = qv[s * 8 + j4];
                xs[j4*4+0]=u.x; xs[j4*4+1]=u.y; xs[j4*4+2]=u.z; xs[j4*4+3]=u.w;
            }
            #pragma unroll
            for (int j = 0; j < 8; ++j) {
                float x = xs[j] * QK_SCALE;
                unsigned int u = __float_as_uint(x);
                float hf = __uint_as_float(u & 0xffff0000u);
                qh[m][s][j] = (short)(u >> 16);
                ql[m][s][j] = (short)(__float_as_uint(x - hf) >> 16);
            }
        }
    }

    bf16x8 onesb;
    #pragma unroll
    for (int j = 0; j < 8; ++j) onesb[j] = (short)0x3F80;   // bf16 1.0

    f32x4 oacc0[4], oacc1[4];
    #pragma unroll
    for (int dt = 0; dt < 4; ++dt) {
        oacc0[dt] = (f32x4){0.f, 0.f, 0.f, 0.f};
        oacc1[dt] = (f32x4){0.f, 0.f, 0.f, 0.f};
    }
    f32x4 lacc0 = (f32x4){0.f,0.f,0.f,0.f}, lacc1 = (f32x4){0.f,0.f,0.f,0.f};
    float mrow0[4], mrow1[4];
    #pragma unroll
    for (int r = 0; r < 4; ++r) { mrow0[r] = -1e30f; mrow1[r] = -1e30f; }

    const unsigned short* kim_h = img + (size_t)(head * NKVIT) * TILE_ELEMS;
    const unsigned short* vtg_h = img + (size_t)(IMG_TILES + head * NKVIT) * TILE_ELEMS;

    // ---- async stage of tile T into LDS buffer B (4 x 16B per thread) ----
    #define STAGE(T, B)                                                 \
    {                                                                   \
        const size_t toff_ = (size_t)(T) * TILE_ELEMS;                  \
        _Pragma("unroll")                                               \
        for (int c_ = 0; c_ < 2; ++c_) {                                \
            const int e8_ = (c_ * 256 + tid) * 8;                       \
            gload_lds16(kim_h + toff_ + e8_, &Kt[B][e8_]);              \
            gload_lds16(vtg_h + toff_ + e8_, &Vt[B][e8_]);              \
        }                                                               \
    }

    STAGE(0, 0)

    // P read address (constant per lane): row l15, col base ^ row-XOR
    const int pswz = (l15 & 7) << 3;

    for (int it = 0; it < NKVIT; ++it) {
        const int cur = it & 1;
        // buf[cur] loads were issued one iteration ago: cheap drain now.
        asm volatile("s_waitcnt vmcnt(0)" ::: "memory");
        __syncthreads();   // all waves staged buf[cur] + finished reading buf[cur^1]
        if (it + 1 < NKVIT) STAGE(it + 1, cur ^ 1)

        const unsigned short* KtC = &Kt[cur][0];
        const unsigned short* VtC = &Vt[cur][0];

        // ---- QK^T for BOTH subtiles: S = Qh K + Ql K (K single bf16) ----
        f32x4 s0[4], s1[4];
        #pragma unroll
        for (int nt = 0; nt < 4; ++nt) {
            s0[nt] = (f32x4){0.f,0.f,0.f,0.f};
            s1[nt] = (f32x4){0.f,0.f,0.f,0.f};
        }
        __builtin_amdgcn_s_setprio(1);
        #pragma unroll
        for (int s = 0; s < 2; ++s) {
            #pragma unroll
            for (int nt = 0; nt < 4; ++nt) {
                const int n = nt * 16 + l15;
                const int off = n * 64 + ((s * 32 + lg * 8) ^ ((n & 7) << 3));
                bf16x8 kf = *(const bf16x8*)(KtC + off);
                s0[nt] = __builtin_amdgcn_mfma_f32_16x16x32_bf16(qh[0][s], kf, s0[nt], 0, 0, 0);
                s0[nt] = __builtin_amdgcn_mfma_f32_16x16x32_bf16(ql[0][s], kf, s0[nt], 0, 0, 0);
                s1[nt] = __builtin_amdgcn_mfma_f32_16x16x32_bf16(qh[1][s], kf, s1[nt], 0, 0, 0);
                s1[nt] = __builtin_amdgcn_mfma_f32_16x16x32_bf16(ql[1][s], kf, s1[nt], 0, 0, 0);
            }
        }
        __builtin_amdgcn_s_setprio(0);

        // ---- softmax (shfl-free common path) ----
        SOFTMAX_BODY(s0, mrow0, oacc0, lacc0)
        SOFTMAX_BODY(s1, mrow1, oacc1, lacc1)

        // ---- P -> per-wave LDS (cvtpk bf16, XOR-swizzled stride 64) ----
        unsigned short* pw = &Pl[w][0];
        bf16x8 pf0[2], pf1[2];
        #pragma unroll
        for (int nt = 0; nt < 4; ++nt) {
            const int cc = nt * 16 + l15;
            unsigned int ua = cvtpk(s0[nt][0], s0[nt][1]);
            unsigned int ub = cvtpk(s0[nt][2], s0[nt][3]);
            const int r0 = lg * 4;
            pw[(r0 + 0) * 64 + (cc ^ (((r0 + 0) & 7) << 3))] = (unsigned short)(ua & 0xffffu);
            pw[(r0 + 1) * 64 + (cc ^ (((r0 + 1) & 7) << 3))] = (unsigned short)(ua >> 16);
            pw[(r0 + 2) * 64 + (cc ^ (((r0 + 2) & 7) << 3))] = (unsigned short)(ub & 0xffffu);
            pw[(r0 + 3) * 64 + (cc ^ (((r0 + 3) & 7) << 3))] = (unsigned short)(ub >> 16);
        }
        #pragma unroll
        for (int s2 = 0; s2 < 2; ++s2)
            pf0[s2] = *(const bf16x8*)(pw + l15 * 64 + ((s2 * 32 + lg * 8) ^ pswz));
        #pragma unroll
        for (int nt = 0; nt < 4; ++nt) {
            const int cc = nt * 16 + l15;
            unsigned int ua = cvtpk(s1[nt][0], s1[nt][1]);
            unsigned int ub = cvtpk(s1[nt][2], s1[nt][3]);
            const int r0 = lg * 4;
            pw[(r0 + 0) * 64 + (cc ^ (((r0 + 0) & 7) << 3))] = (unsigned short)(ua & 0xffffu);
            pw[(r0 + 1) * 64 + (cc ^ (((r0 + 1) & 7) << 3))] = (unsigned short)(ua >> 16);
            pw[(r0 + 2) * 64 + (cc ^ (((r0 + 2) & 7) << 3))] = (unsigned short)(ub & 0xffffu);
            pw[(r0 + 3) * 64 + (cc ^ (((r0 + 3) & 7) << 3))] = (unsigned short)(ub >> 16);
        }
        #pragma unroll
        for (int s2 = 0; s2 < 2; ++s2)
            pf1[s2] = *(const bf16x8*)(pw + l15 * 64 + ((s2 * 32 + lg * 8) ^ pswz));

        // ---- PV + lsum: every V fragment read serves both subtiles ----
        __builtin_amdgcn_s_setprio(1);
        #pragma unroll
        for (int s2 = 0; s2 < 2; ++s2) {
            lacc0 = __builtin_amdgcn_mfma_f32_16x16x32_bf16(pf0[s2], onesb, lacc0, 0, 0, 0);
            lacc1 = __builtin_amdgcn_mfma_f32_16x16x32_bf16(pf1[s2], onesb, lacc1, 0, 0, 0);
            #pragma unroll
            for (int dt = 0; dt < 4; ++dt) {
                const int d = dt * 16 + l15;
                bf16x8 vf = *(const bf16x8*)(VtC + vt_swz(d, s2 * 32 + lg * 8));
                oacc0[dt] = __builtin_amdgcn_mfma_f32_16x16x32_bf16(pf0[s2], vf, oacc0[dt], 0, 0, 0);
                oacc1[dt] = __builtin_amdgcn_mfma_f32_16x16x32_bf16(pf1[s2], vf, oacc1[dt], 0, 0, 0);
            }
        }
        __builtin_amdgcn_s_setprio(0);
    }
    #undef STAGE

    // ---- epilogue ----
    {
        float inv[4];
        #pragma unroll
        for (int r = 0; r < 4; ++r) inv[r] = 1.f / lacc0[r];
        float* ob = O + hb + (size_t)(q0 + w * 32) * Dq;
        #pragma unroll
        for (int dt = 0; dt < 4; ++dt) {
            #pragma unroll
            for (int r = 0; r < 4; ++r)
                ob[(size_t)(lg * 4 + r) * Dq + dt * 16 + l15] = oacc0[dt][r] * inv[r];
        }
    }
    {
        float inv[4];
        #pragma unroll
        for (int r = 0; r < 4; ++r) inv[r] = 1.f / lacc1[r];
        float* ob = O + hb + (size_t)(q0 + w * 32 + 16) * Dq;
        #pragma unroll
        for (int dt = 0; dt < 4; ++dt) {
            #pragma unroll
            for (int r = 0; r < 4; ++r)
                ob[(size_t)(lg * 4 + r) * Dq + dt * 16 + l15] = oacc1[dt][r] * inv[r];
        }
    }
}

// =====================================================================
// Fallback fused fp32 kernel (used when ws too small) — round-3 version
// =====================================================================
__global__ __launch_bounds__(256, 2) void fa_mfma_f32_fused(
    const float* __restrict__ Q, const float* __restrict__ K,
    const float* __restrict__ V, float* __restrict__ O,
    const int* __restrict__ flag)
{
    if (*flag) return;

    __shared__ __align__(16) unsigned short Kh[KVBLK * Dq];
    __shared__ __align__(16) unsigned short Kl[KVBLK * Dq];
    __shared__ __align__(16) unsigned short Vt[Dq * KVBLK];
    __shared__ __align__(16) unsigned short Pl[4][16 * PT_STRIDE];

    const int tid  = threadIdx.x;
    const int lane = tid & 63;
    const int w    = tid >> 6;
    const int l15  = lane & 15;
    const int lg   = lane >> 4;

    const int bid  = (int)blockIdx.x;
    const int blk  = (bid & 7) * (NBLK / 8) + (bid >> 3);
    const int head = blk >> 5;
    const int q0   = (blk & 31) * QBLK;
    const size_t hb = (size_t)head * (Sq * Dq);

    bf16x8 qh[2], ql[2];
    {
        const float* qp = Q + hb + (size_t)(q0 + w * 16 + l15) * Dq + lg * 8;
        #pragma unroll
        for (int s = 0; s < 2; ++s) {
            #pragma unroll
            for (int j = 0; j < 8; ++j) {
                float x = qp[s * 32 + j] * 0.125f;
                unsigned int u = __float_as_uint(x);
                float hf = __uint_as_float(u & 0xffff0000u);
                qh[s][j] = (short)(u >> 16);
                ql[s][j] = (short)(__float_as_uint(x - hf) >> 16);
            }
        }
    }

    f32x4 oacc[4];
    #pragma unroll
    for (int dt = 0; dt < 4; ++dt) oacc[dt] = (f32x4){0.f, 0.f, 0.f, 0.f};
    float mrow[4], lrow[4];
    #pragma unroll
    for (int r = 0; r < 4; ++r) { mrow[r] = -1e30f; lrow[r] = 0.f; }

    const float* kbase = K + hb;
    const float* vbase = V + hb;

    float4 kr[4], vr[4];
    {
        const float4* kt4 = (const float4*)kbase;
        const float4* vt4 = (const float4*)vbase;
        #pragma unroll
        for (int c = 0; c < 4; ++c) { kr[c] = kt4[c * 256 + tid]; vr[c] = vt4[c * 256 + tid]; }
    }

    for (int it = 0; it < NKVIT; ++it) {
        __syncthreads();
        #pragma unroll
        for (int c = 0; c < 4; ++c) {
            const int r  = c * 16 + (tid >> 4);
            const int c0 = (tid & 15) * 4;
            const int sw = c0 ^ ((r & 7) << 3);
            float xs[4] = {kr[c].x, kr[c].y, kr[c].z, kr[c].w};
            unsigned int hp[2], lp[2];
            #pragma unroll
            for (int e = 0; e < 2; ++e) {
                unsigned int u0 = __float_as_uint(xs[2*e]);
                unsigned int u1 = __float_as_uint(xs[2*e+1]);
                hp[e] = (u0 >> 16) | (u1 & 0xffff0000u);
                float h0 = __uint_as_float(u0 & 0xffff0000u);
                float h1 = __uint_as_float(u1 & 0xffff0000u);
                lp[e] = (__float_as_uint(xs[2*e] - h0) >> 16)
                      | (__float_as_uint(xs[2*e+1] - h1) & 0xffff0000u);
            }
            *(uint2*)(Kh + r * 64 + sw) = make_uint2(hp[0], hp[1]);
            *(uint2*)(Kl + r * 64 + sw) = make_uint2(lp[0], lp[1]);
        }
        #pragma unroll
        for (int c = 0; c < 4; ++c) {
            const int kv = c * 16 + (tid >> 4);
            const int d0 = (tid & 15) * 4;
            float xs[4] = {vr[c].x, vr[c].y, vr[c].z, vr[c].w};
            #pragma unroll
            for (int e = 0; e < 4; ++e)
                Vt[vt_swz(d0 + e, kv)] = (unsigned short)f2bf(xs[e]);
        }
        __syncthreads();

        if (it + 1 < NKVIT) {
            const float4* kt4 = (const float4*)(kbase + (size_t)(it + 1) * KVBLK * Dq);
            const float4* vt4 = (const float4*)(vbase + (size_t)(it + 1) * KVBLK * Dq);
            #pragma unroll
            for (int c = 0; c < 4; ++c) { kr[c] = kt4[c * 256 + tid]; vr[c] = vt4[c * 256 + tid]; }
        }

        f32x4 sacc[4];
        #pragma unroll
        for (int nt = 0; nt < 4; ++nt) sacc[nt] = (f32x4){0.f, 0.f, 0.f, 0.f};
        #pragma unroll
        for (int s = 0; s < 2; ++s) {
            #pragma unroll
            for (int nt = 0; nt < 4; ++nt) {
                const int n = nt * 16 + l15;
                const int off = n * 64 + ((s * 32 + lg * 8) ^ ((n & 7) << 3));
                bf16x8 khf = *(const bf16x8*)(Kh + off);
                bf16x8 klf = *(const bf16x8*)(Kl + off);
                sacc[nt] = __builtin_amdgcn_mfma_f32_16x16x32_bf16(qh[s], khf, sacc[nt], 0, 0, 0);
                sacc[nt] = __builtin_amdgcn_mfma_f32_16x16x32_bf16(qh[s], klf, sacc[nt], 0, 0, 0);
                sacc[nt] = __builtin_amdgcn_mfma_f32_16x16x32_bf16(ql[s], khf, sacc[nt], 0, 0, 0);
            }
        }

        float mnew[4], alpha[4];
        #pragma unroll
        for (int r = 0; r < 4; ++r) {
            float t = fmaxf(fmaxf(sacc[0][r], sacc[1][r]), fmaxf(sacc[2][r], sacc[3][r]));
            #pragma unroll
            for (int msk = 1; msk <= 8; msk <<= 1)
                t = fmaxf(t, __shfl_xor(t, msk, 64));
            mnew[r]  = fmaxf(mrow[r], t);
            alpha[r] = __expf(mrow[r] - mnew[r]);
            mrow[r]  = mnew[r];
        }
        float psum[4] = {0.f, 0.f, 0.f, 0.f};
        #pragma unroll
        for (int nt = 0; nt < 4; ++nt) {
            #pragma unroll
            for (int r = 0; r < 4; ++r) {
                float p = __expf(sacc[nt][r] - mnew[r]);
                sacc[nt][r] = p;
                psum[r] += p;
            }
        }
        #pragma unroll
        for (int r = 0; r < 4; ++r) {
            float t = psum[r];
            #pragma unroll
            for (int msk = 1; msk <= 8; msk <<= 1)
                t += __shfl_xor(t, msk, 64);
            lrow[r] = lrow[r] * alpha[r] + t;
        }
        {
            f32x4 av; av[0] = alpha[0]; av[1] = alpha[1]; av[2] = alpha[2]; av[3] = alpha[3];
            #pragma unroll
            for (int dt = 0; dt < 4; ++dt) oacc[dt] *= av;
        }

        unsigned short* pw = &Pl[w][0];
        #pragma unroll
        for (int nt = 0; nt < 4; ++nt) {
            const int cc = nt * 16 + l15;
            #pragma unroll
            for (int r = 0; r < 4; ++r)
                pw[(lg * 4 + r) * PT_STRIDE + cc] = (unsigned short)f2bf(sacc[nt][r]);
        }

        #pragma unroll
        for (int s2 = 0; s2 < 2; ++s2) {
            bf16x8 pf = *(const bf16x8*)(pw + l15 * PT_STRIDE + s2 * 32 + lg * 8);
            #pragma unroll
            for (int dt = 0; dt < 4; ++dt) {
                const int d = dt * 16 + l15;
                bf16x8 vf = *(const bf16x8*)(Vt + vt_swz(d, s2 * 32 + lg * 8));
                oacc[dt] = __builtin_amdgcn_mfma_f32_16x16x32_bf16(pf, vf, oacc[dt], 0, 0, 0);
            }
        }
    }

    float inv4[4];
    #pragma unroll
    for (int r = 0; r < 4; ++r) inv4[r] = 1.f / lrow[r];
    float* ob = O + hb + (size_t)(q0 + w * 16) * Dq;
    #pragma unroll
    for (int dt = 0; dt < 4; ++dt) {
        #pragma unroll
        for (int r = 0; r < 4; ++r)
            ob[(size_t)(lg * 4 + r) * Dq + dt * 16 + l15] = oacc[dt][r] * inv4[r];
    }
}

// =====================================================================
// bf16-input MFMA flash attention (flag=1 robustness; unchanged)
// =====================================================================
__global__ __launch_bounds__(256, 3) void fa_mfma_bf16(
    const unsigned short* __restrict__ Q, const unsigned short* __restrict__ K,
    const unsigned short* __restrict__ V, unsigned short* __restrict__ O,
    const int* __restrict__ flag)
{
    if (!(*flag)) return;

    __shared__ __align__(16) unsigned short Kt[KVBLK * Dq];
    __shared__ __align__(16) unsigned short Vt[Dq * KVBLK];
    __shared__ __align__(16) unsigned short Pl[4][16 * PT_STRIDE];

    const int tid  = threadIdx.x;
    const int lane = tid & 63;
    const int w    = tid >> 6;
    const int l15  = lane & 15;
    const int lg   = lane >> 4;

    const int bid  = (int)blockIdx.x;
    const int blk  = (bid & 7) * (NBLK / 8) + (bid >> 3);
    const int head = blk >> 5;
    const int q0   = (blk & 31) * QBLK;
    const size_t hb = (size_t)head * (Sq * Dq);

    bf16x8 qf[2];
    {
        const bf16x8* qp = (const bf16x8*)(Q + hb + (size_t)(q0 + w * 16 + l15) * Dq);
        qf[0] = qp[lg];
        qf[1] = qp[4 + lg];
    }

    f32x4 oacc[4];
    #pragma unroll
    for (int dt = 0; dt < 4; ++dt) oacc[dt] = (f32x4){0.f, 0.f, 0.f, 0.f};
    float mrow[4], lrow[4];
    #pragma unroll
    for (int r = 0; r < 4; ++r) { mrow[r] = -1e30f; lrow[r] = 0.f; }

    const int sr = tid >> 3;
    const int sc = tid & 7;
    const int kswz_elem = (sc * 8) ^ ((sr & 7) << 3);

    for (int it = 0; it < NKVIT; ++it) {
        const int kv0 = it * KVBLK;
        __syncthreads();
        #pragma unroll
        for (int c = 0; c < 2; ++c) {
            gload_lds16(K + hb + (size_t)(kv0 + c * 32 + sr) * Dq + kswz_elem,
                        Kt + c * 2048 + tid * 8);
        }
        uint4 vreg[2];
        #pragma unroll
        for (int c = 0; c < 2; ++c)
            vreg[c] = *(const uint4*)(V + hb + (size_t)(kv0 + c * 32 + sr) * Dq + sc * 8);

        asm volatile("s_waitcnt vmcnt(0)" ::: "memory");

        #pragma unroll
        for (int c = 0; c < 2; ++c) {
            const int kv = c * 32 + sr;
            unsigned int vu[4] = { vreg[c].x, vreg[c].y, vreg[c].z, vreg[c].w };
            #pragma unroll
            for (int e2 = 0; e2 < 4; ++e2) {
                const int d0 = sc * 8 + e2 * 2;
                Vt[vt_swz(d0,     kv)] = (unsigned short)(vu[e2] & 0xffffu);
                Vt[vt_swz(d0 + 1, kv)] = (unsigned short)(vu[e2] >> 16);
            }
        }
        __syncthreads();

        f32x4 sacc[4];
        #pragma unroll
        for (int nt = 0; nt < 4; ++nt) sacc[nt] = (f32x4){0.f, 0.f, 0.f, 0.f};
        #pragma unroll
        for (int s = 0; s < 2; ++s) {
            #pragma unroll
            for (int nt = 0; nt < 4; ++nt) {
                const int n = nt * 16 + l15;
                bf16x8 kf = *(const bf16x8*)(Kt + n * 64 + ((s * 32 + lg * 8) ^ ((n & 7) << 3)));
                sacc[nt] = __builtin_amdgcn_mfma_f32_16x16x32_bf16(qf[s], kf, sacc[nt], 0, 0, 0);
            }
        }
        #pragma unroll
        for (int nt = 0; nt < 4; ++nt) sacc[nt] *= 0.125f;

        float mnew[4], alpha[4];
        #pragma unroll
        for (int r = 0; r < 4; ++r) {
            float t = fmaxf(fmaxf(sacc[0][r], sacc[1][r]), fmaxf(sacc[2][r], sacc[3][r]));
            #pragma unroll
            for (int msk = 1; msk <= 8; msk <<= 1)
                t = fmaxf(t, __shfl_xor(t, msk, 64));
            mnew[r]  = fmaxf(mrow[r], t);
            alpha[r] = __expf(mrow[r] - mnew[r]);
            mrow[r]  = mnew[r];
        }
        float psum[4] = {0.f, 0.f, 0.f, 0.f};
        #pragma unroll
        for (int nt = 0; nt < 4; ++nt) {
            #pragma unroll
            for (int r = 0; r < 4; ++r) {
                float p = __expf(sacc[nt][r] - mnew[r]);
                sacc[nt][r] = p;
                psum[r] += p;
            }
        }
        #pragma unroll
        for (int r = 0; r < 4; ++r) {
            float t = psum[r];
            #pragma unroll
            for (int msk = 1; msk <= 8; msk <<= 1)
                t += __shfl_xor(t, msk, 64);
            lrow[r] = lrow[r] * alpha[r] + t;
        }
        {
            f32x4 av; av[0] = alpha[0]; av[1] = alpha[1]; av[2] = alpha[2]; av[3] = alpha[3];
            #pragma unroll
            for (int dt = 0; dt < 4; ++dt) oacc[dt] *= av;
        }

        unsigned short* pw = &Pl[w][0];
        #pragma unroll
        for (int nt = 0; nt < 4; ++nt) {
            const int cc = nt * 16 + l15;
            #pragma unroll
            for (int r = 0; r < 4; ++r)
                pw[(lg * 4 + r) * PT_STRIDE + cc] = (unsigned short)f2bf(sacc[nt][r]);
        }

        #pragma unroll
        for (int s2 = 0; s2 < 2; ++s2) {
            bf16x8 pf = *(const bf16x8*)(pw + l15 * PT_STRIDE + s2 * 32 + lg * 8);
            #pragma unroll
            for (int dt = 0; dt < 4; ++dt) {
                const int d = dt * 16 + l15;
                bf16x8 vf = *(const bf16x8*)(Vt + vt_swz(d, s2 * 32 + lg * 8));
                oacc[dt] = __builtin_amdgcn_mfma_f32_16x16x32_bf16(pf, vf, oacc[dt], 0, 0, 0);
            }
        }
    }

    float inv4[4];
    #pragma unroll
    for (int r = 0; r < 4; ++r) inv4[r] = 1.f / lrow[r];
    unsigned short* ob = O + (size_t)(head * Sq + q0 + w * 16) * Dq;
    #pragma unroll
    for (int dt = 0; dt < 4; ++dt) {
        #pragma unroll
        for (int r = 0; r < 4; ++r)
            ob[(size_t)(lg * 4 + r) * Dq + dt * 16 + l15] = (unsigned short)f2bf(oacc[dt][r] * inv4[r]);
    }
}

extern "C" void kernel_launch(void* const* d_in, const int* in_sizes, int n_in,
                              void* d_out, int out_size, void* d_ws, size_t ws_size,
                              hipStream_t stream) {
    int* flag = (int*)d_ws;
    detect_dtype<<<dim3(1), dim3(64), 0, stream>>>((const unsigned int*)d_in[0], flag);
    if (ws_size >= WS_NEEDED) {
        unsigned short* img = (unsigned short*)((char*)d_ws + WS_IMG_OFF);
        convert_kv<<<dim3(IMG_TILES), dim3(256), 0, stream>>>(
            (const float*)d_in[1], (const float*)d_in[2], img, flag);
        fa_mfma_f32_pre<<<dim3(NBLK_P), dim3(256), 0, stream>>>(
            (const float*)d_in[0], img, (float*)d_out, flag);
    } else {
        fa_mfma_f32_fused<<<dim3(NBLK), dim3(256), 0, stream>>>(
            (const float*)d_in[0], (const float*)d_in[1],
            (const float*)d_in[2], (float*)d_out, flag);
    }
    fa_mfma_bf16<<<dim3(NBLK), dim3(256), 0, stream>>>(
        (const unsigned short*)d_in[0], (const unsigned short*)d_in[1],
        (const unsigned short*)d_in[2], (unsigned short*)d_out, flag);
}

// Round 12
// 282.729 us; speedup vs baseline: 1.4319x; 1.4319x over previous
//
#include <hip/hip_runtime.h>

#define Sq 2048
#define Dq 64
#define NH 64                    // B*H heads
#define KVBLK 64                 // KV rows per iteration
#define NKVIT (Sq / KVBLK)       // 32
#define PT_STRIDE 72             // P lds row stride (legacy kernels only)

// ---- pre kernel geometry: 4 waves x 32 q-rows = 128 q-rows per block ----
#define QBLK_P 128
#define NQB_P (Sq / QBLK_P)      // 16
#define NBLK_P (NH * NQB_P)      // 1024 blocks (8-XCD bijective)

// ---- legacy geometry (fused fallback + bf16 path) ----
#define QBLK 64
#define NQB (Sq / QBLK)          // 32
#define NBLK (NH * NQB)          // 2048

#define TILE_ELEMS 4096          // 64x64 bf16 per tile image
#define IMG_TILES (NH * NKVIT)   // 2048 tiles per image
#define IMG_BYTES ((size_t)IMG_TILES * TILE_ELEMS * 2)   // 16,777,216 B
#define WS_IMG_OFF 4096
#define WS_NEEDED (WS_IMG_OFF + 2 * IMG_BYTES)           // ~33.6 MB (K + Vt images)

#define QK_SCALE (0.125f * 1.44269504088896f)  // 1/sqrt(D) * log2(e)
#define DEFER_THR 8.0f                          // T13: P bounded by 2^8

typedef __attribute__((ext_vector_type(8))) short bf16x8;   // 8 bf16 = 4 VGPR
typedef __attribute__((ext_vector_type(4))) float f32x4;    // MFMA acc

// ---------- bf16 helpers ----------
__device__ __forceinline__ float bflo(unsigned int u) {
    union { unsigned int i; float f; } x; x.i = u << 16; return x.f;
}
__device__ __forceinline__ unsigned int f2bf(float f) {
    union { float f; unsigned int i; } x; x.f = f;
    return (x.i + 0x7fffu + ((x.i >> 16) & 1u)) >> 16;   // RNE
}
// packed f32x2 -> bf16x2 (RNE), single VALU op
__device__ __forceinline__ unsigned int cvtpk(float lo, float hi) {
    unsigned int r;
    asm("v_cvt_pk_bf16_f32 %0, %1, %2" : "=v"(r) : "v"(lo), "v"(hi));
    return r;
}

// ---------- dtype detector (deterministic; measured flag=0 on this data) ----------
__global__ void detect_dtype(const unsigned int* __restrict__ Q,
                             int* __restrict__ flag) {
    unsigned int u = Q[threadIdx.x];
    float a = fabsf(bflo(u));
    bool sane = (a >= 9.3e-10f) && (a <= 64.0f);
    unsigned long long b = __ballot(sane);
    if (threadIdx.x == 0) *flag = (__builtin_popcountll(b) >= 48) ? 1 : 0;
}

// ---------- async global->LDS, 16B per lane ----------
__device__ __forceinline__ void gload_lds16(const unsigned short* g, unsigned short* l) {
    __builtin_amdgcn_global_load_lds(
        (const __attribute__((address_space(1))) void*)g,
        (__attribute__((address_space(3))) void*)l, 16, 0, 0);
}

// Vt (= V^T [d][kv]) element index with XOR swizzle (write & read use the same map).
__device__ __forceinline__ int vt_swz(int d, int kv) {
    return (d * KVBLK + kv) ^ ((((d & 7) ^ ((d >> 3) & 7))) << 3);
}

// =====================================================================
// Pre-pass: K -> single RNE bf16 image (swizzled rows), V -> V^T bf16.
// One block per 64x64 tile. ~33.6 MB workspace.
// =====================================================================
__global__ __launch_bounds__(256) void convert_kv(
    const float* __restrict__ K, const float* __restrict__ V,
    unsigned short* __restrict__ img, const int* __restrict__ flag)
{
    if (*flag) return;
    __shared__ __align__(16) unsigned short VtL[TILE_ELEMS];

    const int tile = (int)blockIdx.x;
    const int tid  = threadIdx.x;
    const size_t gbase = (size_t)tile * (KVBLK * Dq);

    unsigned short* kim = img + (size_t)tile * TILE_ELEMS;
    unsigned short* vtg = img + (size_t)(IMG_TILES + tile) * TILE_ELEMS;

    const float4* kt4 = (const float4*)(K + gbase);
    const float4* vt4 = (const float4*)(V + gbase);

    #pragma unroll
    for (int c = 0; c < 4; ++c) {
        const int r  = (c * 256 + tid) >> 4;     // row 0..63
        const int c0 = (tid & 15) * 4;           // col base
        {
            float4 u4 = kt4[c * 256 + tid];
            unsigned int p0 = f2bf(u4.x) | (f2bf(u4.y) << 16);   // RNE bf16
            unsigned int p1 = f2bf(u4.z) | (f2bf(u4.w) << 16);
            const int sw = c0 ^ ((r & 7) << 3);
            *(uint2*)(kim + r * 64 + sw) = make_uint2(p0, p1);
        }
        {
            float4 u4 = vt4[c * 256 + tid];
            float xs[4] = {u4.x, u4.y, u4.z, u4.w};
            #pragma unroll
            for (int e = 0; e < 4; ++e)
                VtL[vt_swz(c0 + e, r)] = (unsigned short)f2bf(xs[e]);
        }
    }
    __syncthreads();
    #pragma unroll
    for (int c = 0; c < 2; ++c)
        *(uint4*)(vtg + (c * 256 + tid) * 8) = *(const uint4*)(VtL + (c * 256 + tid) * 8);
}

// ---- softmax common-path (shfl-free defer-max; full reduce only on grow) ----
#define SOFTMAX_BODY(SACC, MR, OA, LA)                                          \
{                                                                               \
    float rmax[4];                                                              \
    _Pragma("unroll")                                                           \
    for (int r = 0; r < 4; ++r)                                                 \
        rmax[r] = fmaxf(fmaxf(SACC[0][r], SACC[1][r]),                          \
                        fmaxf(SACC[2][r], SACC[3][r]));                         \
    bool grow = (rmax[0] > MR[0] + DEFER_THR) | (rmax[1] > MR[1] + DEFER_THR)   \
              | (rmax[2] > MR[2] + DEFER_THR) | (rmax[3] > MR[3] + DEFER_THR);  \
    if (__any(grow)) {                                                          \
        f32x4 av;                                                               \
        _Pragma("unroll")                                                       \
        for (int r = 0; r < 4; ++r) {                                           \
            float t = rmax[r];                                                  \
            _Pragma("unroll")                                                   \
            for (int msk = 1; msk <= 8; msk <<= 1)                              \
                t = fmaxf(t, __shfl_xor(t, msk, 64));                           \
            float mnew = fmaxf(MR[r], t);                                       \
            av[r] = exp2f(MR[r] - mnew);                                        \
            MR[r] = mnew;                                                       \
        }                                                                       \
        _Pragma("unroll")                                                       \
        for (int dt = 0; dt < 4; ++dt) OA[dt] *= av;                            \
        LA *= av;                                                               \
    }                                                                           \
    _Pragma("unroll")                                                           \
    for (int nt = 0; nt < 4; ++nt) {                                            \
        _Pragma("unroll")                                                       \
        for (int r = 0; r < 4; ++r)                                             \
            SACC[nt][r] = exp2f(SACC[nt][r] - MR[r]);                           \
    }                                                                           \
}

// =====================================================================
// Main fp32-input MFMA flash attention: 4 waves x 32 q-rows, single
// bf16 K image (Q hi/lo split: S = Qh K + Ql K), double-buffered
// staging, XOR-swizzled P buffer at stride 64 -> LDS = 40960 B exactly.
// __launch_bounds__(256,3): compiler emits ~80 VGPR (no spill); HW then
// schedules 4 blocks/CU since LDS=40960 and 80 <= 128-VGPR quantum.
// (256,4) was a 64-VGPR spill catastrophe - round 11.)
// =====================================================================
__global__ __launch_bounds__(256, 3) void fa_mfma_f32_pre(
    const float* __restrict__ Q, const unsigned short* __restrict__ img,
    float* __restrict__ O, const int* __restrict__ flag)
{
    if (*flag) return;

    __shared__ __align__(16) unsigned short Kt[2][TILE_ELEMS];   // 16 KiB
    __shared__ __align__(16) unsigned short Vt[2][TILE_ELEMS];   // 16 KiB
    __shared__ __align__(16) unsigned short Pl[4][16 * 64];      // 8 KiB, XOR-swizzled

    const int tid  = threadIdx.x;
    const int lane = tid & 63;
    const int w    = tid >> 6;       // wave 0..3
    const int l15  = lane & 15;
    const int lg   = lane >> 4;

    // XCD-aware bijective swizzle: 1024 blocks = 8 XCDs x 128
    const int bid  = (int)blockIdx.x;
    const int blk  = (bid & 7) * (NBLK_P / 8) + (bid >> 3);
    const int head = blk >> 4;               // 16 q-blocks per head
    const int q0   = (blk & 15) * QBLK_P;
    const size_t hb = (size_t)head * (Sq * Dq);

    // ---- Q fragments: 2 subtiles (m), scaled by 1/8*log2e, hi/lo split ----
    bf16x8 qh[2][2], ql[2][2];   // [m][s]
    #pragma unroll
    for (int m = 0; m < 2; ++m) {
        const float4* qv = (const float4*)(Q + hb
            + (size_t)(q0 + w * 32 + m * 16 + l15) * Dq + lg * 8);
        #pragma unroll
        for (int s = 0; s < 2; ++s) {
            float xs[8];
            #pragma unroll
            for (int j4 = 0; j4 < 2; ++j4) {
                float4 u = qv[s * 8 + j4];
                xs[j4*4+0]=u.x; xs[j4*4+1]=u.y; xs[j4*4+2]=u.z; xs[j4*4+3]=u.w;
            }
            #pragma unroll
            for (int j = 0; j < 8; ++j) {
                float x = xs[j] * QK_SCALE;
                unsigned int u = __float_as_uint(x);
                float hf = __uint_as_float(u & 0xffff0000u);
                qh[m][s][j] = (short)(u >> 16);
                ql[m][s][j] = (short)(__float_as_uint(x - hf) >> 16);
            }
        }
    }

    bf16x8 onesb;
    #pragma unroll
    for (int j = 0; j < 8; ++j) onesb[j] = (short)0x3F80;   // bf16 1.0

    f32x4 oacc0[4], oacc1[4];
    #pragma unroll
    for (int dt = 0; dt < 4; ++dt) {
        oacc0[dt] = (f32x4){0.f, 0.f, 0.f, 0.f};
        oacc1[dt] = (f32x4){0.f, 0.f, 0.f, 0.f};
    }
    f32x4 lacc0 = (f32x4){0.f,0.f,0.f,0.f}, lacc1 = (f32x4){0.f,0.f,0.f,0.f};
    float mrow0[4], mrow1[4];
    #pragma unroll
    for (int r = 0; r < 4; ++r) { mrow0[r] = -1e30f; mrow1[r] = -1e30f; }

    const unsigned short* kim_h = img + (size_t)(head * NKVIT) * TILE_ELEMS;
    const unsigned short* vtg_h = img + (size_t)(IMG_TILES + head * NKVIT) * TILE_ELEMS;

    // ---- async stage of tile T into LDS buffer B (4 x 16B per thread) ----
    #define STAGE(T, B)                                                 \
    {                                                                   \
        const size_t toff_ = (size_t)(T) * TILE_ELEMS;                  \
        _Pragma("unroll")                                               \
        for (int c_ = 0; c_ < 2; ++c_) {                                \
            const int e8_ = (c_ * 256 + tid) * 8;                       \
            gload_lds16(kim_h + toff_ + e8_, &Kt[B][e8_]);              \
            gload_lds16(vtg_h + toff_ + e8_, &Vt[B][e8_]);              \
        }                                                               \
    }

    STAGE(0, 0)

    // P read address (constant per lane): row l15, col base ^ row-XOR
    const int pswz = (l15 & 7) << 3;

    for (int it = 0; it < NKVIT; ++it) {
        const int cur = it & 1;
        // buf[cur] loads were issued one iteration ago: cheap drain now.
        asm volatile("s_waitcnt vmcnt(0)" ::: "memory");
        __syncthreads();   // all waves staged buf[cur] + finished reading buf[cur^1]
        if (it + 1 < NKVIT) STAGE(it + 1, cur ^ 1)

        const unsigned short* KtC = &Kt[cur][0];
        const unsigned short* VtC = &Vt[cur][0];

        // ---- QK^T for BOTH subtiles: S = Qh K + Ql K (K single bf16) ----
        f32x4 s0[4], s1[4];
        #pragma unroll
        for (int nt = 0; nt < 4; ++nt) {
            s0[nt] = (f32x4){0.f,0.f,0.f,0.f};
            s1[nt] = (f32x4){0.f,0.f,0.f,0.f};
        }
        __builtin_amdgcn_s_setprio(1);
        #pragma unroll
        for (int s = 0; s < 2; ++s) {
            #pragma unroll
            for (int nt = 0; nt < 4; ++nt) {
                const int n = nt * 16 + l15;
                const int off = n * 64 + ((s * 32 + lg * 8) ^ ((n & 7) << 3));
                bf16x8 kf = *(const bf16x8*)(KtC + off);
                s0[nt] = __builtin_amdgcn_mfma_f32_16x16x32_bf16(qh[0][s], kf, s0[nt], 0, 0, 0);
                s0[nt] = __builtin_amdgcn_mfma_f32_16x16x32_bf16(ql[0][s], kf, s0[nt], 0, 0, 0);
                s1[nt] = __builtin_amdgcn_mfma_f32_16x16x32_bf16(qh[1][s], kf, s1[nt], 0, 0, 0);
                s1[nt] = __builtin_amdgcn_mfma_f32_16x16x32_bf16(ql[1][s], kf, s1[nt], 0, 0, 0);
            }
        }
        __builtin_amdgcn_s_setprio(0);

        // ---- softmax (shfl-free common path) ----
        SOFTMAX_BODY(s0, mrow0, oacc0, lacc0)
        SOFTMAX_BODY(s1, mrow1, oacc1, lacc1)

        // ---- P -> per-wave LDS (cvtpk bf16, XOR-swizzled stride 64) ----
        unsigned short* pw = &Pl[w][0];
        bf16x8 pf0[2], pf1[2];
        #pragma unroll
        for (int nt = 0; nt < 4; ++nt) {
            const int cc = nt * 16 + l15;
            unsigned int ua = cvtpk(s0[nt][0], s0[nt][1]);
            unsigned int ub = cvtpk(s0[nt][2], s0[nt][3]);
            const int r0 = lg * 4;
            pw[(r0 + 0) * 64 + (cc ^ (((r0 + 0) & 7) << 3))] = (unsigned short)(ua & 0xffffu);
            pw[(r0 + 1) * 64 + (cc ^ (((r0 + 1) & 7) << 3))] = (unsigned short)(ua >> 16);
            pw[(r0 + 2) * 64 + (cc ^ (((r0 + 2) & 7) << 3))] = (unsigned short)(ub & 0xffffu);
            pw[(r0 + 3) * 64 + (cc ^ (((r0 + 3) & 7) << 3))] = (unsigned short)(ub >> 16);
        }
        #pragma unroll
        for (int s2 = 0; s2 < 2; ++s2)
            pf0[s2] = *(const bf16x8*)(pw + l15 * 64 + ((s2 * 32 + lg * 8) ^ pswz));
        #pragma unroll
        for (int nt = 0; nt < 4; ++nt) {
            const int cc = nt * 16 + l15;
            unsigned int ua = cvtpk(s1[nt][0], s1[nt][1]);
            unsigned int ub = cvtpk(s1[nt][2], s1[nt][3]);
            const int r0 = lg * 4;
            pw[(r0 + 0) * 64 + (cc ^ (((r0 + 0) & 7) << 3))] = (unsigned short)(ua & 0xffffu);
            pw[(r0 + 1) * 64 + (cc ^ (((r0 + 1) & 7) << 3))] = (unsigned short)(ua >> 16);
            pw[(r0 + 2) * 64 + (cc ^ (((r0 + 2) & 7) << 3))] = (unsigned short)(ub & 0xffffu);
            pw[(r0 + 3) * 64 + (cc ^ (((r0 + 3) & 7) << 3))] = (unsigned short)(ub >> 16);
        }
        #pragma unroll
        for (int s2 = 0; s2 < 2; ++s2)
            pf1[s2] = *(const bf16x8*)(pw + l15 * 64 + ((s2 * 32 + lg * 8) ^ pswz));

        // ---- PV + lsum: every V fragment read serves both subtiles ----
        __builtin_amdgcn_s_setprio(1);
        #pragma unroll
        for (int s2 = 0; s2 < 2; ++s2) {
            lacc0 = __builtin_amdgcn_mfma_f32_16x16x32_bf16(pf0[s2], onesb, lacc0, 0, 0, 0);
            lacc1 = __builtin_amdgcn_mfma_f32_16x16x32_bf16(pf1[s2], onesb, lacc1, 0, 0, 0);
            #pragma unroll
            for (int dt = 0; dt < 4; ++dt) {
                const int d = dt * 16 + l15;
                bf16x8 vf = *(const bf16x8*)(VtC + vt_swz(d, s2 * 32 + lg * 8));
                oacc0[dt] = __builtin_amdgcn_mfma_f32_16x16x32_bf16(pf0[s2], vf, oacc0[dt], 0, 0, 0);
                oacc1[dt] = __builtin_amdgcn_mfma_f32_16x16x32_bf16(pf1[s2], vf, oacc1[dt], 0, 0, 0);
            }
        }
        __builtin_amdgcn_s_setprio(0);
    }
    #undef STAGE

    // ---- epilogue ----
    {
        float inv[4];
        #pragma unroll
        for (int r = 0; r < 4; ++r) inv[r] = 1.f / lacc0[r];
        float* ob = O + hb + (size_t)(q0 + w * 32) * Dq;
        #pragma unroll
        for (int dt = 0; dt < 4; ++dt) {
            #pragma unroll
            for (int r = 0; r < 4; ++r)
                ob[(size_t)(lg * 4 + r) * Dq + dt * 16 + l15] = oacc0[dt][r] * inv[r];
        }
    }
    {
        float inv[4];
        #pragma unroll
        for (int r = 0; r < 4; ++r) inv[r] = 1.f / lacc1[r];
        float* ob = O + hb + (size_t)(q0 + w * 32 + 16) * Dq;
        #pragma unroll
        for (int dt = 0; dt < 4; ++dt) {
            #pragma unroll
            for (int r = 0; r < 4; ++r)
                ob[(size_t)(lg * 4 + r) * Dq + dt * 16 + l15] = oacc1[dt][r] * inv[r];
        }
    }
}

// =====================================================================
// Fallback fused fp32 kernel (used when ws too small) — round-3 version
// =====================================================================
__global__ __launch_bounds__(256, 2) void fa_mfma_f32_fused(
    const float* __restrict__ Q, const float* __restrict__ K,
    const float* __restrict__ V, float* __restrict__ O,
    const int* __restrict__ flag)
{
    if (*flag) return;

    __shared__ __align__(16) unsigned short Kh[KVBLK * Dq];
    __shared__ __align__(16) unsigned short Kl[KVBLK * Dq];
    __shared__ __align__(16) unsigned short Vt[Dq * KVBLK];
    __shared__ __align__(16) unsigned short Pl[4][16 * PT_STRIDE];

    const int tid  = threadIdx.x;
    const int lane = tid & 63;
    const int w    = tid >> 6;
    const int l15  = lane & 15;
    const int lg   = lane >> 4;

    const int bid  = (int)blockIdx.x;
    const int blk  = (bid & 7) * (NBLK / 8) + (bid >> 3);
    const int head = blk >> 5;
    const int q0   = (blk & 31) * QBLK;
    const size_t hb = (size_t)head * (Sq * Dq);

    bf16x8 qh[2], ql[2];
    {
        const float* qp = Q + hb + (size_t)(q0 + w * 16 + l15) * Dq + lg * 8;
        #pragma unroll
        for (int s = 0; s < 2; ++s) {
            #pragma unroll
            for (int j = 0; j < 8; ++j) {
                float x = qp[s * 32 + j] * 0.125f;
                unsigned int u = __float_as_uint(x);
                float hf = __uint_as_float(u & 0xffff0000u);
                qh[s][j] = (short)(u >> 16);
                ql[s][j] = (short)(__float_as_uint(x - hf) >> 16);
            }
        }
    }

    f32x4 oacc[4];
    #pragma unroll
    for (int dt = 0; dt < 4; ++dt) oacc[dt] = (f32x4){0.f, 0.f, 0.f, 0.f};
    float mrow[4], lrow[4];
    #pragma unroll
    for (int r = 0; r < 4; ++r) { mrow[r] = -1e30f; lrow[r] = 0.f; }

    const float* kbase = K + hb;
    const float* vbase = V + hb;

    float4 kr[4], vr[4];
    {
        const float4* kt4 = (const float4*)kbase;
        const float4* vt4 = (const float4*)vbase;
        #pragma unroll
        for (int c = 0; c < 4; ++c) { kr[c] = kt4[c * 256 + tid]; vr[c] = vt4[c * 256 + tid]; }
    }

    for (int it = 0; it < NKVIT; ++it) {
        __syncthreads();
        #pragma unroll
        for (int c = 0; c < 4; ++c) {
            const int r  = c * 16 + (tid >> 4);
            const int c0 = (tid & 15) * 4;
            const int sw = c0 ^ ((r & 7) << 3);
            float xs[4] = {kr[c].x, kr[c].y, kr[c].z, kr[c].w};
            unsigned int hp[2], lp[2];
            #pragma unroll
            for (int e = 0; e < 2; ++e) {
                unsigned int u0 = __float_as_uint(xs[2*e]);
                unsigned int u1 = __float_as_uint(xs[2*e+1]);
                hp[e] = (u0 >> 16) | (u1 & 0xffff0000u);
                float h0 = __uint_as_float(u0 & 0xffff0000u);
                float h1 = __uint_as_float(u1 & 0xffff0000u);
                lp[e] = (__float_as_uint(xs[2*e] - h0) >> 16)
                      | (__float_as_uint(xs[2*e+1] - h1) & 0xffff0000u);
            }
            *(uint2*)(Kh + r * 64 + sw) = make_uint2(hp[0], hp[1]);
            *(uint2*)(Kl + r * 64 + sw) = make_uint2(lp[0], lp[1]);
        }
        #pragma unroll
        for (int c = 0; c < 4; ++c) {
            const int kv = c * 16 + (tid >> 4);
            const int d0 = (tid & 15) * 4;
            float xs[4] = {vr[c].x, vr[c].y, vr[c].z, vr[c].w};
            #pragma unroll
            for (int e = 0; e < 4; ++e)
                Vt[vt_swz(d0 + e, kv)] = (unsigned short)f2bf(xs[e]);
        }
        __syncthreads();

        if (it + 1 < NKVIT) {
            const float4* kt4 = (const float4*)(kbase + (size_t)(it + 1) * KVBLK * Dq);
            const float4* vt4 = (const float4*)(vbase + (size_t)(it + 1) * KVBLK * Dq);
            #pragma unroll
            for (int c = 0; c < 4; ++c) { kr[c] = kt4[c * 256 + tid]; vr[c] = vt4[c * 256 + tid]; }
        }

        f32x4 sacc[4];
        #pragma unroll
        for (int nt = 0; nt < 4; ++nt) sacc[nt] = (f32x4){0.f, 0.f, 0.f, 0.f};
        #pragma unroll
        for (int s = 0; s < 2; ++s) {
            #pragma unroll
            for (int nt = 0; nt < 4; ++nt) {
                const int n = nt * 16 + l15;
                const int off = n * 64 + ((s * 32 + lg * 8) ^ ((n & 7) << 3));
                bf16x8 khf = *(const bf16x8*)(Kh + off);
                bf16x8 klf = *(const bf16x8*)(Kl + off);
                sacc[nt] = __builtin_amdgcn_mfma_f32_16x16x32_bf16(qh[s], khf, sacc[nt], 0, 0, 0);
                sacc[nt] = __builtin_amdgcn_mfma_f32_16x16x32_bf16(qh[s], klf, sacc[nt], 0, 0, 0);
                sacc[nt] = __builtin_amdgcn_mfma_f32_16x16x32_bf16(ql[s], khf, sacc[nt], 0, 0, 0);
            }
        }

        float mnew[4], alpha[4];
        #pragma unroll
        for (int r = 0; r < 4; ++r) {
            float t = fmaxf(fmaxf(sacc[0][r], sacc[1][r]), fmaxf(sacc[2][r], sacc[3][r]));
            #pragma unroll
            for (int msk = 1; msk <= 8; msk <<= 1)
                t = fmaxf(t, __shfl_xor(t, msk, 64));
            mnew[r]  = fmaxf(mrow[r], t);
            alpha[r] = __expf(mrow[r] - mnew[r]);
            mrow[r]  = mnew[r];
        }
        float psum[4] = {0.f, 0.f, 0.f, 0.f};
        #pragma unroll
        for (int nt = 0; nt < 4; ++nt) {
            #pragma unroll
            for (int r = 0; r < 4; ++r) {
                float p = __expf(sacc[nt][r] - mnew[r]);
                sacc[nt][r] = p;
                psum[r] += p;
            }
        }
        #pragma unroll
        for (int r = 0; r < 4; ++r) {
            float t = psum[r];
            #pragma unroll
            for (int msk = 1; msk <= 8; msk <<= 1)
                t += __shfl_xor(t, msk, 64);
            lrow[r] = lrow[r] * alpha[r] + t;
        }
        {
            f32x4 av; av[0] = alpha[0]; av[1] = alpha[1]; av[2] = alpha[2]; av[3] = alpha[3];
            #pragma unroll
            for (int dt = 0; dt < 4; ++dt) oacc[dt] *= av;
        }

        unsigned short* pw = &Pl[w][0];
        #pragma unroll
        for (int nt = 0; nt < 4; ++nt) {
            const int cc = nt * 16 + l15;
            #pragma unroll
            for (int r = 0; r < 4; ++r)
                pw[(lg * 4 + r) * PT_STRIDE + cc] = (unsigned short)f2bf(sacc[nt][r]);
        }

        #pragma unroll
        for (int s2 = 0; s2 < 2; ++s2) {
            bf16x8 pf = *(const bf16x8*)(pw + l15 * PT_STRIDE + s2 * 32 + lg * 8);
            #pragma unroll
            for (int dt = 0; dt < 4; ++dt) {
                const int d = dt * 16 + l15;
                bf16x8 vf = *(const bf16x8*)(Vt + vt_swz(d, s2 * 32 + lg * 8));
                oacc[dt] = __builtin_amdgcn_mfma_f32_16x16x32_bf16(pf, vf, oacc[dt], 0, 0, 0);
            }
        }
    }

    float inv4[4];
    #pragma unroll
    for (int r = 0; r < 4; ++r) inv4[r] = 1.f / lrow[r];
    float* ob = O + hb + (size_t)(q0 + w * 16) * Dq;
    #pragma unroll
    for (int dt = 0; dt < 4; ++dt) {
        #pragma unroll
        for (int r = 0; r < 4; ++r)
            ob[(size_t)(lg * 4 + r) * Dq + dt * 16 + l15] = oacc[dt][r] * inv4[r];
    }
}

// =====================================================================
// bf16-input MFMA flash attention (flag=1 robustness; unchanged)
// =====================================================================
__global__ __launch_bounds__(256, 3) void fa_mfma_bf16(
    const unsigned short* __restrict__ Q, const unsigned short* __restrict__ K,
    const unsigned short* __restrict__ V, unsigned short* __restrict__ O,
    const int* __restrict__ flag)
{
    if (!(*flag)) return;

    __shared__ __align__(16) unsigned short Kt[KVBLK * Dq];
    __shared__ __align__(16) unsigned short Vt[Dq * KVBLK];
    __shared__ __align__(16) unsigned short Pl[4][16 * PT_STRIDE];

    const int tid  = threadIdx.x;
    const int lane = tid & 63;
    const int w    = tid >> 6;
    const int l15  = lane & 15;
    const int lg   = lane >> 4;

    const int bid  = (int)blockIdx.x;
    const int blk  = (bid & 7) * (NBLK / 8) + (bid >> 3);
    const int head = blk >> 5;
    const int q0   = (blk & 31) * QBLK;
    const size_t hb = (size_t)head * (Sq * Dq);

    bf16x8 qf[2];
    {
        const bf16x8* qp = (const bf16x8*)(Q + hb + (size_t)(q0 + w * 16 + l15) * Dq);
        qf[0] = qp[lg];
        qf[1] = qp[4 + lg];
    }

    f32x4 oacc[4];
    #pragma unroll
    for (int dt = 0; dt < 4; ++dt) oacc[dt] = (f32x4){0.f, 0.f, 0.f, 0.f};
    float mrow[4], lrow[4];
    #pragma unroll
    for (int r = 0; r < 4; ++r) { mrow[r] = -1e30f; lrow[r] = 0.f; }

    const int sr = tid >> 3;
    const int sc = tid & 7;
    const int kswz_elem = (sc * 8) ^ ((sr & 7) << 3);

    for (int it = 0; it < NKVIT; ++it) {
        const int kv0 = it * KVBLK;
        __syncthreads();
        #pragma unroll
        for (int c = 0; c < 2; ++c) {
            gload_lds16(K + hb + (size_t)(kv0 + c * 32 + sr) * Dq + kswz_elem,
                        Kt + c * 2048 + tid * 8);
        }
        uint4 vreg[2];
        #pragma unroll
        for (int c = 0; c < 2; ++c)
            vreg[c] = *(const uint4*)(V + hb + (size_t)(kv0 + c * 32 + sr) * Dq + sc * 8);

        asm volatile("s_waitcnt vmcnt(0)" ::: "memory");

        #pragma unroll
        for (int c = 0; c < 2; ++c) {
            const int kv = c * 32 + sr;
            unsigned int vu[4] = { vreg[c].x, vreg[c].y, vreg[c].z, vreg[c].w };
            #pragma unroll
            for (int e2 = 0; e2 < 4; ++e2) {
                const int d0 = sc * 8 + e2 * 2;
                Vt[vt_swz(d0,     kv)] = (unsigned short)(vu[e2] & 0xffffu);
                Vt[vt_swz(d0 + 1, kv)] = (unsigned short)(vu[e2] >> 16);
            }
        }
        __syncthreads();

        f32x4 sacc[4];
        #pragma unroll
        for (int nt = 0; nt < 4; ++nt) sacc[nt] = (f32x4){0.f, 0.f, 0.f, 0.f};
        #pragma unroll
        for (int s = 0; s < 2; ++s) {
            #pragma unroll
            for (int nt = 0; nt < 4; ++nt) {
                const int n = nt * 16 + l15;
                bf16x8 kf = *(const bf16x8*)(Kt + n * 64 + ((s * 32 + lg * 8) ^ ((n & 7) << 3)));
                sacc[nt] = __builtin_amdgcn_mfma_f32_16x16x32_bf16(qf[s], kf, sacc[nt], 0, 0, 0);
            }
        }
        #pragma unroll
        for (int nt = 0; nt < 4; ++nt) sacc[nt] *= 0.125f;

        float mnew[4], alpha[4];
        #pragma unroll
        for (int r = 0; r < 4; ++r) {
            float t = fmaxf(fmaxf(sacc[0][r], sacc[1][r]), fmaxf(sacc[2][r], sacc[3][r]));
            #pragma unroll
            for (int msk = 1; msk <= 8; msk <<= 1)
                t = fmaxf(t, __shfl_xor(t, msk, 64));
            mnew[r]  = fmaxf(mrow[r], t);
            alpha[r] = __expf(mrow[r] - mnew[r]);
            mrow[r]  = mnew[r];
        }
        float psum[4] = {0.f, 0.f, 0.f, 0.f};
        #pragma unroll
        for (int nt = 0; nt < 4; ++nt) {
            #pragma unroll
            for (int r = 0; r < 4; ++r) {
                float p = __expf(sacc[nt][r] - mnew[r]);
                sacc[nt][r] = p;
                psum[r] += p;
            }
        }
        #pragma unroll
        for (int r = 0; r < 4; ++r) {
            float t = psum[r];
            #pragma unroll
            for (int msk = 1; msk <= 8; msk <<= 1)
                t += __shfl_xor(t, msk, 64);
            lrow[r] = lrow[r] * alpha[r] + t;
        }
        {
            f32x4 av; av[0] = alpha[0]; av[1] = alpha[1]; av[2] = alpha[2]; av[3] = alpha[3];
            #pragma unroll
            for (int dt = 0; dt < 4; ++dt) oacc[dt] *= av;
        }

        unsigned short* pw = &Pl[w][0];
        #pragma unroll
        for (int nt = 0; nt < 4; ++nt) {
            const int cc = nt * 16 + l15;
            #pragma unroll
            for (int r = 0; r < 4; ++r)
                pw[(lg * 4 + r) * PT_STRIDE + cc] = (unsigned short)f2bf(sacc[nt][r]);
        }

        #pragma unroll
        for (int s2 = 0; s2 < 2; ++s2) {
            bf16x8 pf = *(const bf16x8*)(pw + l15 * PT_STRIDE + s2 * 32 + lg * 8);
            #pragma unroll
            for (int dt = 0; dt < 4; ++dt) {
                const int d = dt * 16 + l15;
                bf16x8 vf = *(const bf16x8*)(Vt + vt_swz(d, s2 * 32 + lg * 8));
                oacc[dt] = __builtin_amdgcn_mfma_f32_16x16x32_bf16(pf, vf, oacc[dt], 0, 0, 0);
            }
        }
    }

    float inv4[4];
    #pragma unroll
    for (int r = 0; r < 4; ++r) inv4[r] = 1.f / lrow[r];
    unsigned short* ob = O + (size_t)(head * Sq + q0 + w * 16) * Dq;
    #pragma unroll
    for (int dt = 0; dt < 4; ++dt) {
        #pragma unroll
        for (int r = 0; r < 4; ++r)
            ob[(size_t)(lg * 4 + r) * Dq + dt * 16 + l15] = (unsigned short)f2bf(oacc[dt][r] * inv4[r]);
    }
}

extern "C" void kernel_launch(void* const* d_in, const int* in_sizes, int n_in,
                              void* d_out, int out_size, void* d_ws, size_t ws_size,
                              hipStream_t stream) {
    int* flag = (int*)d_ws;
    detect_dtype<<<dim3(1), dim3(64), 0, stream>>>((const unsigned int*)d_in[0], flag);
    if (ws_size >= WS_NEEDED) {
        unsigned short* img = (unsigned short*)((char*)d_ws + WS_IMG_OFF);
        convert_kv<<<dim3(IMG_TILES), dim3(256), 0, stream>>>(
            (const float*)d_in[1], (const float*)d_in[2], img, flag);
        fa_mfma_f32_pre<<<dim3(NBLK_P), dim3(256), 0, stream>>>(
            (const float*)d_in[0], img, (float*)d_out, flag);
    } else {
        fa_mfma_f32_fused<<<dim3(NBLK), dim3(256), 0, stream>>>(
            (const float*)d_in[0], (const float*)d_in[1],
            (const float*)d_in[2], (float*)d_out, flag);
    }
    fa_mfma_bf16<<<dim3(NBLK), dim3(256), 0, stream>>>(
        (const unsigned short*)d_in[0], (const unsigned short*)d_in[1],
        (const unsigned short*)d_in[2], (unsigned short*)d_out, flag);
}

// Round 13
// 260.186 us; speedup vs baseline: 1.5560x; 1.0866x over previous
//
#include <hip/hip_runtime.h>

#define Sq 2048
#define Dq 64
#define NH 64                    // B*H heads
#define KVBLK 64                 // KV rows per iteration
#define NKVIT (Sq / KVBLK)       // 32
#define PT_STRIDE 72             // P lds row stride (legacy kernels only)

// ---- pre kernel geometry: 4 waves x 32 q-rows = 128 q-rows per block ----
#define QBLK_P 128
#define NQB_P (Sq / QBLK_P)      // 16
#define NBLK_P (NH * NQB_P)      // 1024 blocks (8-XCD bijective)

// ---- legacy geometry (fused fallback + bf16 path) ----
#define QBLK 64
#define NQB (Sq / QBLK)          // 32
#define NBLK (NH * NQB)          // 2048

#define TILE_ELEMS 4096          // 64x64 bf16 per tile image
#define IMG_TILES (NH * NKVIT)   // 2048 tiles per image
#define IMG_BYTES ((size_t)IMG_TILES * TILE_ELEMS * 2)   // 16,777,216 B
#define WS_IMG_OFF 4096
#define WS_NEEDED (WS_IMG_OFF + 2 * IMG_BYTES)           // ~33.6 MB (K + Vt images)

#define QK_SCALE (0.125f * 1.44269504088896f)  // 1/sqrt(D) * log2(e)
#define DEFER_THR 8.0f                          // T13: P bounded by 2^8

typedef __attribute__((ext_vector_type(8))) short bf16x8;   // 8 bf16 = 4 VGPR
typedef __attribute__((ext_vector_type(4))) float f32x4;    // MFMA acc

// ---------- bf16 helpers ----------
__device__ __forceinline__ float bflo(unsigned int u) {
    union { unsigned int i; float f; } x; x.i = u << 16; return x.f;
}
__device__ __forceinline__ unsigned int f2bf(float f) {
    union { float f; unsigned int i; } x; x.f = f;
    return (x.i + 0x7fffu + ((x.i >> 16) & 1u)) >> 16;   // RNE
}
// packed f32x2 -> bf16x2 (RNE), single VALU op
__device__ __forceinline__ unsigned int cvtpk(float lo, float hi) {
    unsigned int r;
    asm("v_cvt_pk_bf16_f32 %0, %1, %2" : "=v"(r) : "v"(lo), "v"(hi));
    return r;
}

// ---------- dtype detector (deterministic; measured flag=0 on this data) ----------
__global__ void detect_dtype(const unsigned int* __restrict__ Q,
                             int* __restrict__ flag) {
    unsigned int u = Q[threadIdx.x];
    float a = fabsf(bflo(u));
    bool sane = (a >= 9.3e-10f) && (a <= 64.0f);
    unsigned long long b = __ballot(sane);
    if (threadIdx.x == 0) *flag = (__builtin_popcountll(b) >= 48) ? 1 : 0;
}

// ---------- async global->LDS, 16B per lane ----------
__device__ __forceinline__ void gload_lds16(const unsigned short* g, unsigned short* l) {
    __builtin_amdgcn_global_load_lds(
        (const __attribute__((address_space(1))) void*)g,
        (__attribute__((address_space(3))) void*)l, 16, 0, 0);
}

// Vt (= V^T [d][kv]) element index with XOR swizzle (write & read use the same map).
__device__ __forceinline__ int vt_swz(int d, int kv) {
    return (d * KVBLK + kv) ^ ((((d & 7) ^ ((d >> 3) & 7))) << 3);
}

// =====================================================================
// Pre-pass: K -> single RNE bf16 image (swizzled rows), V -> V^T bf16.
// One block per 64x64 tile. ~33.6 MB workspace. (verified r10/r12)
// =====================================================================
__global__ __launch_bounds__(256) void convert_kv(
    const float* __restrict__ K, const float* __restrict__ V,
    unsigned short* __restrict__ img, const int* __restrict__ flag)
{
    if (*flag) return;
    __shared__ __align__(16) unsigned short VtL[TILE_ELEMS];

    const int tile = (int)blockIdx.x;
    const int tid  = threadIdx.x;
    const size_t gbase = (size_t)tile * (KVBLK * Dq);

    unsigned short* kim = img + (size_t)tile * TILE_ELEMS;
    unsigned short* vtg = img + (size_t)(IMG_TILES + tile) * TILE_ELEMS;

    const float4* kt4 = (const float4*)(K + gbase);
    const float4* vt4 = (const float4*)(V + gbase);

    #pragma unroll
    for (int c = 0; c < 4; ++c) {
        const int r  = (c * 256 + tid) >> 4;     // row 0..63
        const int c0 = (tid & 15) * 4;           // col base
        {
            float4 u4 = kt4[c * 256 + tid];
            unsigned int p0 = f2bf(u4.x) | (f2bf(u4.y) << 16);   // RNE bf16
            unsigned int p1 = f2bf(u4.z) | (f2bf(u4.w) << 16);
            const int sw = c0 ^ ((r & 7) << 3);
            *(uint2*)(kim + r * 64 + sw) = make_uint2(p0, p1);
        }
        {
            float4 u4 = vt4[c * 256 + tid];
            float xs[4] = {u4.x, u4.y, u4.z, u4.w};
            #pragma unroll
            for (int e = 0; e < 4; ++e)
                VtL[vt_swz(c0 + e, r)] = (unsigned short)f2bf(xs[e]);
        }
    }
    __syncthreads();
    #pragma unroll
    for (int c = 0; c < 2; ++c)
        *(uint4*)(vtg + (c * 256 + tid) * 8) = *(const uint4*)(VtL + (c * 256 + tid) * 8);
}

// =====================================================================
// Main fp32-input MFMA flash attention, round 13:
// Swapped QK^T (S^T = mfma(K,Q)) with permuted kv decomposition
//   kv(nt, m) = (nt&1)*32 + (m>>2)*8 + (nt>>1)*4 + (m&3)
// so each lane holds exactly its PV B-fragment's P values ->
// P transpose is pure in-register cvtpk (no LDS, no shfl).
// K image UNCHANGED (rows read permuted, per-row XOR (krow&7)<<3).
// O^T accumulators (q lane-local -> scalar m/alpha per lane).
// Double-buffered staging w/ explicit vmcnt (verified r9-r12).
// =====================================================================
__global__ __launch_bounds__(256, 3) void fa_mfma_f32_pre(
    const float* __restrict__ Q, const unsigned short* __restrict__ img,
    float* __restrict__ O, const int* __restrict__ flag)
{
    if (*flag) return;

    __shared__ __align__(16) unsigned short Kt[2][TILE_ELEMS];   // 16 KiB
    __shared__ __align__(16) unsigned short Vt[2][TILE_ELEMS];   // 16 KiB

    const int tid  = threadIdx.x;
    const int lane = tid & 63;
    const int w    = tid >> 6;       // wave 0..3
    const int l15  = lane & 15;
    const int lg   = lane >> 4;

    // XCD-aware bijective swizzle: 1024 blocks = 8 XCDs x 128
    const int bid  = (int)blockIdx.x;
    const int blk  = (bid & 7) * (NBLK_P / 8) + (bid >> 3);
    const int head = blk >> 4;               // 16 q-blocks per head
    const int q0   = (blk & 15) * QBLK_P;
    const size_t hb = (size_t)head * (Sq * Dq);

    // ---- Q fragments: 2 subtiles (m), scaled by 1/8*log2e, hi/lo split ----
    // As B-operand: B[k=lg*8+j][n=l15] = Q[q-row l15][d = s*32 + lg*8 + j]
    bf16x8 qh[2][2], ql[2][2];   // [m][s]
    #pragma unroll
    for (int m = 0; m < 2; ++m) {
        const float4* qv = (const float4*)(Q + hb
            + (size_t)(q0 + w * 32 + m * 16 + l15) * Dq + lg * 8);
        #pragma unroll
        for (int s = 0; s < 2; ++s) {
            float xs[8];
            #pragma unroll
            for (int j4 = 0; j4 < 2; ++j4) {
                float4 u = qv[s * 8 + j4];
                xs[j4*4+0]=u.x; xs[j4*4+1]=u.y; xs[j4*4+2]=u.z; xs[j4*4+3]=u.w;
            }
            #pragma unroll
            for (int j = 0; j < 8; ++j) {
                float x = xs[j] * QK_SCALE;
                unsigned int u = __float_as_uint(x);
                float hf = __uint_as_float(u & 0xffff0000u);
                qh[m][s][j] = (short)(u >> 16);
                ql[m][s][j] = (short)(__float_as_uint(x - hf) >> 16);
            }
        }
    }

    bf16x8 onesb;
    #pragma unroll
    for (int j = 0; j < 8; ++j) onesb[j] = (short)0x3F80;   // bf16 1.0

    // O^T accumulators: lane holds O[q=l15][d = dt*16 + lg*4 + r]
    f32x4 oacc0[4], oacc1[4];
    #pragma unroll
    for (int dt = 0; dt < 4; ++dt) {
        oacc0[dt] = (f32x4){0.f, 0.f, 0.f, 0.f};
        oacc1[dt] = (f32x4){0.f, 0.f, 0.f, 0.f};
    }
    f32x4 lacc0 = (f32x4){0.f,0.f,0.f,0.f}, lacc1 = (f32x4){0.f,0.f,0.f,0.f};
    float m0 = -1e30f, m1 = -1e30f;   // one scalar per lane: q is lane-local

    const unsigned short* kim_h = img + (size_t)(head * NKVIT) * TILE_ELEMS;
    const unsigned short* vtg_h = img + (size_t)(IMG_TILES + head * NKVIT) * TILE_ELEMS;

    // ---- async stage of tile T into LDS buffer B (4 x 16B per thread) ----
    #define STAGE(T, B)                                                 \
    {                                                                   \
        const size_t toff_ = (size_t)(T) * TILE_ELEMS;                  \
        _Pragma("unroll")                                               \
        for (int c_ = 0; c_ < 2; ++c_) {                                \
            const int e8_ = (c_ * 256 + tid) * 8;                       \
            gload_lds16(kim_h + toff_ + e8_, &Kt[B][e8_]);              \
            gload_lds16(vtg_h + toff_ + e8_, &Vt[B][e8_]);              \
        }                                                               \
    }

    STAGE(0, 0)

    // permuted K A-frag row for this lane (per nt): krow = ntbase + krb
    const int krb = ((l15 >> 2) << 3) + (l15 & 3);

    for (int it = 0; it < NKVIT; ++it) {
        const int cur = it & 1;
        asm volatile("s_waitcnt vmcnt(0)" ::: "memory");
        __syncthreads();   // all waves staged buf[cur] + finished reading buf[cur^1]
        if (it + 1 < NKVIT) STAGE(it + 1, cur ^ 1)

        const unsigned short* KtC = &Kt[cur][0];
        const unsigned short* VtC = &Vt[cur][0];

        // ---- swapped QK^T: s[nt][r] = S[q=l15][kv=(nt&1)*32+lg*8+(nt>>1)*4+r]
        f32x4 s0[4], s1[4];
        #pragma unroll
        for (int nt = 0; nt < 4; ++nt) {
            s0[nt] = (f32x4){0.f,0.f,0.f,0.f};
            s1[nt] = (f32x4){0.f,0.f,0.f,0.f};
        }
        __builtin_amdgcn_s_setprio(1);
        #pragma unroll
        for (int s = 0; s < 2; ++s) {
            #pragma unroll
            for (int nt = 0; nt < 4; ++nt) {
                const int krow = ((nt & 1) << 5) + ((nt >> 1) << 2) + krb;
                const int off  = krow * 64 + ((s * 32 + lg * 8) ^ ((krow & 7) << 3));
                bf16x8 kf = *(const bf16x8*)(KtC + off);
                s0[nt] = __builtin_amdgcn_mfma_f32_16x16x32_bf16(kf, qh[0][s], s0[nt], 0, 0, 0);
                s0[nt] = __builtin_amdgcn_mfma_f32_16x16x32_bf16(kf, ql[0][s], s0[nt], 0, 0, 0);
                s1[nt] = __builtin_amdgcn_mfma_f32_16x16x32_bf16(kf, qh[1][s], s1[nt], 0, 0, 0);
                s1[nt] = __builtin_amdgcn_mfma_f32_16x16x32_bf16(kf, ql[1][s], s1[nt], 0, 0, 0);
            }
        }
        __builtin_amdgcn_s_setprio(0);

        // ---- softmax: q lane-local -> scalar m; full reduce only on grow ----
        float lm0 = s0[0][0], lm1 = s1[0][0];
        #pragma unroll
        for (int nt = 0; nt < 4; ++nt) {
            #pragma unroll
            for (int r = 0; r < 4; ++r) {
                lm0 = fmaxf(lm0, s0[nt][r]);
                lm1 = fmaxf(lm1, s1[nt][r]);
            }
        }
        if (__any((lm0 > m0 + DEFER_THR) | (lm1 > m1 + DEFER_THR))) {
            float t0 = lm0, t1 = lm1;
            t0 = fmaxf(t0, __shfl_xor(t0, 16, 64));
            t0 = fmaxf(t0, __shfl_xor(t0, 32, 64));
            t1 = fmaxf(t1, __shfl_xor(t1, 16, 64));
            t1 = fmaxf(t1, __shfl_xor(t1, 32, 64));
            float n0 = fmaxf(m0, t0), n1 = fmaxf(m1, t1);
            float a0 = exp2f(m0 - n0);
            float a1 = exp2f(m1 - n1);
            m0 = n0; m1 = n1;
            #pragma unroll
            for (int dt = 0; dt < 4; ++dt) { oacc0[dt] *= a0; oacc1[dt] *= a1; }
            lacc0 *= a0; lacc1 *= a1;
        }
        #pragma unroll
        for (int nt = 0; nt < 4; ++nt) {
            #pragma unroll
            for (int r = 0; r < 4; ++r) {
                s0[nt][r] = exp2f(s0[nt][r] - m0);   // <= 2^8
                s1[nt][r] = exp2f(s1[nt][r] - m1);
            }
        }

        // ---- in-register P pack + PV + lsum ----
        // p[j] = P[q=l15][kv=s2*32+lg*8+j] = s[s2+2*(j>>2)][j&3]
        #pragma unroll
        for (int s2 = 0; s2 < 2; ++s2) {
            union { unsigned int u[4]; bf16x8 v; } p0, p1;
            p0.u[0] = cvtpk(s0[s2    ][0], s0[s2    ][1]);
            p0.u[1] = cvtpk(s0[s2    ][2], s0[s2    ][3]);
            p0.u[2] = cvtpk(s0[s2 + 2][0], s0[s2 + 2][1]);
            p0.u[3] = cvtpk(s0[s2 + 2][2], s0[s2 + 2][3]);
            p1.u[0] = cvtpk(s1[s2    ][0], s1[s2    ][1]);
            p1.u[1] = cvtpk(s1[s2    ][2], s1[s2    ][3]);
            p1.u[2] = cvtpk(s1[s2 + 2][0], s1[s2 + 2][1]);
            p1.u[3] = cvtpk(s1[s2 + 2][2], s1[s2 + 2][3]);
            __builtin_amdgcn_s_setprio(1);
            lacc0 = __builtin_amdgcn_mfma_f32_16x16x32_bf16(onesb, p0.v, lacc0, 0, 0, 0);
            lacc1 = __builtin_amdgcn_mfma_f32_16x16x32_bf16(onesb, p1.v, lacc1, 0, 0, 0);
            #pragma unroll
            for (int dt = 0; dt < 4; ++dt) {
                bf16x8 vf = *(const bf16x8*)(VtC + vt_swz(dt * 16 + l15, s2 * 32 + lg * 8));
                oacc0[dt] = __builtin_amdgcn_mfma_f32_16x16x32_bf16(vf, p0.v, oacc0[dt], 0, 0, 0);
                oacc1[dt] = __builtin_amdgcn_mfma_f32_16x16x32_bf16(vf, p1.v, oacc1[dt], 0, 0, 0);
            }
            __builtin_amdgcn_s_setprio(0);
        }
    }
    #undef STAGE

    // ---- epilogue: O^T layout -> float4 per d-quad ----
    {
        const float inv = 1.f / lacc0[0];
        float* ob = O + hb + (size_t)(q0 + w * 32 + l15) * Dq;
        #pragma unroll
        for (int dt = 0; dt < 4; ++dt) {
            float4 v; v.x = oacc0[dt][0] * inv; v.y = oacc0[dt][1] * inv;
                      v.z = oacc0[dt][2] * inv; v.w = oacc0[dt][3] * inv;
            *(float4*)(ob + dt * 16 + lg * 4) = v;
        }
    }
    {
        const float inv = 1.f / lacc1[0];
        float* ob = O + hb + (size_t)(q0 + w * 32 + 16 + l15) * Dq;
        #pragma unroll
        for (int dt = 0; dt < 4; ++dt) {
            float4 v; v.x = oacc1[dt][0] * inv; v.y = oacc1[dt][1] * inv;
                      v.z = oacc1[dt][2] * inv; v.w = oacc1[dt][3] * inv;
            *(float4*)(ob + dt * 16 + lg * 4) = v;
        }
    }
}

// =====================================================================
// Fallback fused fp32 kernel (used when ws too small) — round-3 version
// =====================================================================
__global__ __launch_bounds__(256, 2) void fa_mfma_f32_fused(
    const float* __restrict__ Q, const float* __restrict__ K,
    const float* __restrict__ V, float* __restrict__ O,
    const int* __restrict__ flag)
{
    if (*flag) return;

    __shared__ __align__(16) unsigned short Kh[KVBLK * Dq];
    __shared__ __align__(16) unsigned short Kl[KVBLK * Dq];
    __shared__ __align__(16) unsigned short Vt[Dq * KVBLK];
    __shared__ __align__(16) unsigned short Pl[4][16 * PT_STRIDE];

    const int tid  = threadIdx.x;
    const int lane = tid & 63;
    const int w    = tid >> 6;
    const int l15  = lane & 15;
    const int lg   = lane >> 4;

    const int bid  = (int)blockIdx.x;
    const int blk  = (bid & 7) * (NBLK / 8) + (bid >> 3);
    const int head = blk >> 5;
    const int q0   = (blk & 31) * QBLK;
    const size_t hb = (size_t)head * (Sq * Dq);

    bf16x8 qh[2], ql[2];
    {
        const float* qp = Q + hb + (size_t)(q0 + w * 16 + l15) * Dq + lg * 8;
        #pragma unroll
        for (int s = 0; s < 2; ++s) {
            #pragma unroll
            for (int j = 0; j < 8; ++j) {
                float x = qp[s * 32 + j] * 0.125f;
                unsigned int u = __float_as_uint(x);
                float hf = __uint_as_float(u & 0xffff0000u);
                qh[s][j] = (short)(u >> 16);
                ql[s][j] = (short)(__float_as_uint(x - hf) >> 16);
            }
        }
    }

    f32x4 oacc[4];
    #pragma unroll
    for (int dt = 0; dt < 4; ++dt) oacc[dt] = (f32x4){0.f, 0.f, 0.f, 0.f};
    float mrow[4], lrow[4];
    #pragma unroll
    for (int r = 0; r < 4; ++r) { mrow[r] = -1e30f; lrow[r] = 0.f; }

    const float* kbase = K + hb;
    const float* vbase = V + hb;

    float4 kr[4], vr[4];
    {
        const float4* kt4 = (const float4*)kbase;
        const float4* vt4 = (const float4*)vbase;
        #pragma unroll
        for (int c = 0; c < 4; ++c) { kr[c] = kt4[c * 256 + tid]; vr[c] = vt4[c * 256 + tid]; }
    }

    for (int it = 0; it < NKVIT; ++it) {
        __syncthreads();
        #pragma unroll
        for (int c = 0; c < 4; ++c) {
            const int r  = c * 16 + (tid >> 4);
            const int c0 = (tid & 15) * 4;
            const int sw = c0 ^ ((r & 7) << 3);
            float xs[4] = {kr[c].x, kr[c].y, kr[c].z, kr[c].w};
            unsigned int hp[2], lp[2];
            #pragma unroll
            for (int e = 0; e < 2; ++e) {
                unsigned int u0 = __float_as_uint(xs[2*e]);
                unsigned int u1 = __float_as_uint(xs[2*e+1]);
                hp[e] = (u0 >> 16) | (u1 & 0xffff0000u);
                float h0 = __uint_as_float(u0 & 0xffff0000u);
                float h1 = __uint_as_float(u1 & 0xffff0000u);
                lp[e] = (__float_as_uint(xs[2*e] - h0) >> 16)
                      | (__float_as_uint(xs[2*e+1] - h1) & 0xffff0000u);
            }
            *(uint2*)(Kh + r * 64 + sw) = make_uint2(hp[0], hp[1]);
            *(uint2*)(Kl + r * 64 + sw) = make_uint2(lp[0], lp[1]);
        }
        #pragma unroll
        for (int c = 0; c < 4; ++c) {
            const int kv = c * 16 + (tid >> 4);
            const int d0 = (tid & 15) * 4;
            float xs[4] = {vr[c].x, vr[c].y, vr[c].z, vr[c].w};
            #pragma unroll
            for (int e = 0; e < 4; ++e)
                Vt[vt_swz(d0 + e, kv)] = (unsigned short)f2bf(xs[e]);
        }
        __syncthreads();

        if (it + 1 < NKVIT) {
            const float4* kt4 = (const float4*)(kbase + (size_t)(it + 1) * KVBLK * Dq);
            const float4* vt4 = (const float4*)(vbase + (size_t)(it + 1) * KVBLK * Dq);
            #pragma unroll
            for (int c = 0; c < 4; ++c) { kr[c] = kt4[c * 256 + tid]; vr[c] = vt4[c * 256 + tid]; }
        }

        f32x4 sacc[4];
        #pragma unroll
        for (int nt = 0; nt < 4; ++nt) sacc[nt] = (f32x4){0.f, 0.f, 0.f, 0.f};
        #pragma unroll
        for (int s = 0; s < 2; ++s) {
            #pragma unroll
            for (int nt = 0; nt < 4; ++nt) {
                const int n = nt * 16 + l15;
                const int off = n * 64 + ((s * 32 + lg * 8) ^ ((n & 7) << 3));
                bf16x8 khf = *(const bf16x8*)(Kh + off);
                bf16x8 klf = *(const bf16x8*)(Kl + off);
                sacc[nt] = __builtin_amdgcn_mfma_f32_16x16x32_bf16(qh[s], khf, sacc[nt], 0, 0, 0);
                sacc[nt] = __builtin_amdgcn_mfma_f32_16x16x32_bf16(qh[s], klf, sacc[nt], 0, 0, 0);
                sacc[nt] = __builtin_amdgcn_mfma_f32_16x16x32_bf16(ql[s], khf, sacc[nt], 0, 0, 0);
            }
        }

        float mnew[4], alpha[4];
        #pragma unroll
        for (int r = 0; r < 4; ++r) {
            float t = fmaxf(fmaxf(sacc[0][r], sacc[1][r]), fmaxf(sacc[2][r], sacc[3][r]));
            #pragma unroll
            for (int msk = 1; msk <= 8; msk <<= 1)
                t = fmaxf(t, __shfl_xor(t, msk, 64));
            mnew[r]  = fmaxf(mrow[r], t);
            alpha[r] = __expf(mrow[r] - mnew[r]);
            mrow[r]  = mnew[r];
        }
        float psum[4] = {0.f, 0.f, 0.f, 0.f};
        #pragma unroll
        for (int nt = 0; nt < 4; ++nt) {
            #pragma unroll
            for (int r = 0; r < 4; ++r) {
                float p = __expf(sacc[nt][r] - mnew[r]);
                sacc[nt][r] = p;
                psum[r] += p;
            }
        }
        #pragma unroll
        for (int r = 0; r < 4; ++r) {
            float t = psum[r];
            #pragma unroll
            for (int msk = 1; msk <= 8; msk <<= 1)
                t += __shfl_xor(t, msk, 64);
            lrow[r] = lrow[r] * alpha[r] + t;
        }
        {
            f32x4 av; av[0] = alpha[0]; av[1] = alpha[1]; av[2] = alpha[2]; av[3] = alpha[3];
            #pragma unroll
            for (int dt = 0; dt < 4; ++dt) oacc[dt] *= av;
        }

        unsigned short* pw = &Pl[w][0];
        #pragma unroll
        for (int nt = 0; nt < 4; ++nt) {
            const int cc = nt * 16 + l15;
            #pragma unroll
            for (int r = 0; r < 4; ++r)
                pw[(lg * 4 + r) * PT_STRIDE + cc] = (unsigned short)f2bf(sacc[nt][r]);
        }

        #pragma unroll
        for (int s2 = 0; s2 < 2; ++s2) {
            bf16x8 pf = *(const bf16x8*)(pw + l15 * PT_STRIDE + s2 * 32 + lg * 8);
            #pragma unroll
            for (int dt = 0; dt < 4; ++dt) {
                const int d = dt * 16 + l15;
                bf16x8 vf = *(const bf16x8*)(Vt + vt_swz(d, s2 * 32 + lg * 8));
                oacc[dt] = __builtin_amdgcn_mfma_f32_16x16x32_bf16(pf, vf, oacc[dt], 0, 0, 0);
            }
        }
    }

    float inv4[4];
    #pragma unroll
    for (int r = 0; r < 4; ++r) inv4[r] = 1.f / lrow[r];
    float* ob = O + hb + (size_t)(q0 + w * 16) * Dq;
    #pragma unroll
    for (int dt = 0; dt < 4; ++dt) {
        #pragma unroll
        for (int r = 0; r < 4; ++r)
            ob[(size_t)(lg * 4 + r) * Dq + dt * 16 + l15] = oacc[dt][r] * inv4[r];
    }
}

// =====================================================================
// bf16-input MFMA flash attention (flag=1 robustness; unchanged)
// =====================================================================
__global__ __launch_bounds__(256, 3) void fa_mfma_bf16(
    const unsigned short* __restrict__ Q, const unsigned short* __restrict__ K,
    const unsigned short* __restrict__ V, unsigned short* __restrict__ O,
    const int* __restrict__ flag)
{
    if (!(*flag)) return;

    __shared__ __align__(16) unsigned short Kt[KVBLK * Dq];
    __shared__ __align__(16) unsigned short Vt[Dq * KVBLK];
    __shared__ __align__(16) unsigned short Pl[4][16 * PT_STRIDE];

    const int tid  = threadIdx.x;
    const int lane = tid & 63;
    const int w    = tid >> 6;
    const int l15  = lane & 15;
    const int lg   = lane >> 4;

    const int bid  = (int)blockIdx.x;
    const int blk  = (bid & 7) * (NBLK / 8) + (bid >> 3);
    const int head = blk >> 5;
    const int q0   = (blk & 31) * QBLK;
    const size_t hb = (size_t)head * (Sq * Dq);

    bf16x8 qf[2];
    {
        const bf16x8* qp = (const bf16x8*)(Q + hb + (size_t)(q0 + w * 16 + l15) * Dq);
        qf[0] = qp[lg];
        qf[1] = qp[4 + lg];
    }

    f32x4 oacc[4];
    #pragma unroll
    for (int dt = 0; dt < 4; ++dt) oacc[dt] = (f32x4){0.f, 0.f, 0.f, 0.f};
    float mrow[4], lrow[4];
    #pragma unroll
    for (int r = 0; r < 4; ++r) { mrow[r] = -1e30f; lrow[r] = 0.f; }

    const int sr = tid >> 3;
    const int sc = tid & 7;
    const int kswz_elem = (sc * 8) ^ ((sr & 7) << 3);

    for (int it = 0; it < NKVIT; ++it) {
        const int kv0 = it * KVBLK;
        __syncthreads();
        #pragma unroll
        for (int c = 0; c < 2; ++c) {
            gload_lds16(K + hb + (size_t)(kv0 + c * 32 + sr) * Dq + kswz_elem,
                        Kt + c * 2048 + tid * 8);
        }
        uint4 vreg[2];
        #pragma unroll
        for (int c = 0; c < 2; ++c)
            vreg[c] = *(const uint4*)(V + hb + (size_t)(kv0 + c * 32 + sr) * Dq + sc * 8);

        asm volatile("s_waitcnt vmcnt(0)" ::: "memory");

        #pragma unroll
        for (int c = 0; c < 2; ++c) {
            const int kv = c * 32 + sr;
            unsigned int vu[4] = { vreg[c].x, vreg[c].y, vreg[c].z, vreg[c].w };
            #pragma unroll
            for (int e2 = 0; e2 < 4; ++e2) {
                const int d0 = sc * 8 + e2 * 2;
                Vt[vt_swz(d0,     kv)] = (unsigned short)(vu[e2] & 0xffffu);
                Vt[vt_swz(d0 + 1, kv)] = (unsigned short)(vu[e2] >> 16);
            }
        }
        __syncthreads();

        f32x4 sacc[4];
        #pragma unroll
        for (int nt = 0; nt < 4; ++nt) sacc[nt] = (f32x4){0.f, 0.f, 0.f, 0.f};
        #pragma unroll
        for (int s = 0; s < 2; ++s) {
            #pragma unroll
            for (int nt = 0; nt < 4; ++nt) {
                const int n = nt * 16 + l15;
                bf16x8 kf = *(const bf16x8*)(Kt + n * 64 + ((s * 32 + lg * 8) ^ ((n & 7) << 3)));
                sacc[nt] = __builtin_amdgcn_mfma_f32_16x16x32_bf16(qf[s], kf, sacc[nt], 0, 0, 0);
            }
        }
        #pragma unroll
        for (int nt = 0; nt < 4; ++nt) sacc[nt] *= 0.125f;

        float mnew[4], alpha[4];
        #pragma unroll
        for (int r = 0; r < 4; ++r) {
            float t = fmaxf(fmaxf(sacc[0][r], sacc[1][r]), fmaxf(sacc[2][r], sacc[3][r]));
            #pragma unroll
            for (int msk = 1; msk <= 8; msk <<= 1)
                t = fmaxf(t, __shfl_xor(t, msk, 64));
            mnew[r]  = fmaxf(mrow[r], t);
            alpha[r] = __expf(mrow[r] - mnew[r]);
            mrow[r]  = mnew[r];
        }
        float psum[4] = {0.f, 0.f, 0.f, 0.f};
        #pragma unroll
        for (int nt = 0; nt < 4; ++nt) {
            #pragma unroll
            for (int r = 0; r < 4; ++r) {
                float p = __expf(sacc[nt][r] - mnew[r]);
                sacc[nt][r] = p;
                psum[r] += p;
            }
        }
        #pragma unroll
        for (int r = 0; r < 4; ++r) {
            float t = psum[r];
            #pragma unroll
            for (int msk = 1; msk <= 8; msk <<= 1)
                t += __shfl_xor(t, msk, 64);
            lrow[r] = lrow[r] * alpha[r] + t;
        }
        {
            f32x4 av; av[0] = alpha[0]; av[1] = alpha[1]; av[2] = alpha[2]; av[3] = alpha[3];
            #pragma unroll
            for (int dt = 0; dt < 4; ++dt) oacc[dt] *= av;
        }

        unsigned short* pw = &Pl[w][0];
        #pragma unroll
        for (int nt = 0; nt < 4; ++nt) {
            const int cc = nt * 16 + l15;
            #pragma unroll
            for (int r = 0; r < 4; ++r)
                pw[(lg * 4 + r) * PT_STRIDE + cc] = (unsigned short)f2bf(sacc[nt][r]);
        }

        #pragma unroll
        for (int s2 = 0; s2 < 2; ++s2) {
            bf16x8 pf = *(const bf16x8*)(pw + l15 * PT_STRIDE + s2 * 32 + lg * 8);
            #pragma unroll
            for (int dt = 0; dt < 4; ++dt) {
                const int d = dt * 16 + l15;
                bf16x8 vf = *(const bf16x8*)(Vt + vt_swz(d, s2 * 32 + lg * 8));
                oacc[dt] = __builtin_amdgcn_mfma_f32_16x16x32_bf16(pf, vf, oacc[dt], 0, 0, 0);
            }
        }
    }

    float inv4[4];
    #pragma unroll
    for (int r = 0; r < 4; ++r) inv4[r] = 1.f / lrow[r];
    unsigned short* ob = O + (size_t)(head * Sq + q0 + w * 16) * Dq;
    #pragma unroll
    for (int dt = 0; dt < 4; ++dt) {
        #pragma unroll
        for (int r = 0; r < 4; ++r)
            ob[(size_t)(lg * 4 + r) * Dq + dt * 16 + l15] = (unsigned short)f2bf(oacc[dt][r] * inv4[r]);
    }
}

extern "C" void kernel_launch(void* const* d_in, const int* in_sizes, int n_in,
                              void* d_out, int out_size, void* d_ws, size_t ws_size,
                              hipStream_t stream) {
    int* flag = (int*)d_ws;
    detect_dtype<<<dim3(1), dim3(64), 0, stream>>>((const unsigned int*)d_in[0], flag);
    if (ws_size >= WS_NEEDED) {
        unsigned short* img = (unsigned short*)((char*)d_ws + WS_IMG_OFF);
        convert_kv<<<dim3(IMG_TILES), dim3(256), 0, stream>>>(
            (const float*)d_in[1], (const float*)d_in[2], img, flag);
        fa_mfma_f32_pre<<<dim3(NBLK_P), dim3(256), 0, stream>>>(
            (const float*)d_in[0], img, (float*)d_out, flag);
    } else {
        fa_mfma_f32_fused<<<dim3(NBLK), dim3(256), 0, stream>>>(
            (const float*)d_in[0], (const float*)d_in[1],
            (const float*)d_in[2], (float*)d_out, flag);
    }
    fa_mfma_bf16<<<dim3(NBLK), dim3(256), 0, stream>>>(
        (const unsigned short*)d_in[0], (const unsigned short*)d_in[1],
        (const unsigned short*)d_in[2], (unsigned short*)d_out, flag);
}

// Round 14
// 234.614 us; speedup vs baseline: 1.7256x; 1.1090x over previous
//
#include <hip/hip_runtime.h>

#define Sq 2048
#define Dq 64
#define NH 64                    // B*H heads
#define KVBLK 64                 // KV rows per iteration
#define NKVIT (Sq / KVBLK)       // 32
#define PT_STRIDE 72             // P lds row stride (legacy kernels only)

// ---- pre kernel geometry: 4 waves x 32 q-rows = 128 q-rows per block ----
#define QBLK_P 128
#define NQB_P (Sq / QBLK_P)      // 16
#define NBLK_P (NH * NQB_P)      // 1024 blocks (8-XCD bijective)

// ---- legacy geometry (fused fallback + bf16 path) ----
#define QBLK 64
#define NQB (Sq / QBLK)          // 32
#define NBLK (NH * NQB)          // 2048

#define TILE_ELEMS 4096          // 64x64 bf16 per tile image
#define IMG_TILES (NH * NKVIT)   // 2048 tiles per image
#define IMG_BYTES ((size_t)IMG_TILES * TILE_ELEMS * 2)   // 16,777,216 B
#define WS_IMG_OFF 4096
#define WS_NEEDED (WS_IMG_OFF + 2 * IMG_BYTES)           // ~33.6 MB (K + Vt images)

#define QK_SCALE (0.125f * 1.44269504088896f)  // 1/sqrt(D) * log2(e)
#define DEFER_THR 8.0f                          // T13: P bounded by 2^8

typedef __attribute__((ext_vector_type(8))) short bf16x8;   // 8 bf16 = 4 VGPR
typedef __attribute__((ext_vector_type(4))) float f32x4;    // MFMA acc

// ---------- bf16 helpers ----------
__device__ __forceinline__ float bflo(unsigned int u) {
    union { unsigned int i; float f; } x; x.i = u << 16; return x.f;
}
__device__ __forceinline__ unsigned int f2bf(float f) {
    union { float f; unsigned int i; } x; x.f = f;
    return (x.i + 0x7fffu + ((x.i >> 16) & 1u)) >> 16;   // RNE
}
// packed f32x2 -> bf16x2 (RNE), single VALU op
__device__ __forceinline__ unsigned int cvtpk(float lo, float hi) {
    unsigned int r;
    asm("v_cvt_pk_bf16_f32 %0, %1, %2" : "=v"(r) : "v"(lo), "v"(hi));
    return r;
}

// ---------- dtype detector (deterministic; measured flag=0 on this data) ----------
__global__ void detect_dtype(const unsigned int* __restrict__ Q,
                             int* __restrict__ flag) {
    unsigned int u = Q[threadIdx.x];
    float a = fabsf(bflo(u));
    bool sane = (a >= 9.3e-10f) && (a <= 64.0f);
    unsigned long long b = __ballot(sane);
    if (threadIdx.x == 0) *flag = (__builtin_popcountll(b) >= 48) ? 1 : 0;
}

// ---------- async global->LDS, 16B per lane ----------
__device__ __forceinline__ void gload_lds16(const unsigned short* g, unsigned short* l) {
    __builtin_amdgcn_global_load_lds(
        (const __attribute__((address_space(1))) void*)g,
        (__attribute__((address_space(3))) void*)l, 16, 0, 0);
}

// Vt (= V^T [d][kv]) element index with XOR swizzle (write & read use the same map).
__device__ __forceinline__ int vt_swz(int d, int kv) {
    return (d * KVBLK + kv) ^ ((((d & 7) ^ ((d >> 3) & 7))) << 3);
}
// K image granule XOR matched to the permuted A-frag row set (bits 0,1,3 of row
// vary within a fragment; bits 2,5 are per-tile constants) -> uniform 8-granule
// spread per wave (2 lanes/granule = free), and a per-lane-constant read XOR.
__device__ __forceinline__ int k_g(int r) {
    return (r & 3) | (((r >> 3) & 1) << 2);
}

// =====================================================================
// Pre-pass: K -> single RNE bf16 image (rows stored with k_g granule
// XOR), V -> V^T bf16. One block per 64x64 tile. ~33.6 MB workspace.
// =====================================================================
__global__ __launch_bounds__(256) void convert_kv(
    const float* __restrict__ K, const float* __restrict__ V,
    unsigned short* __restrict__ img, const int* __restrict__ flag)
{
    if (*flag) return;
    __shared__ __align__(16) unsigned short VtL[TILE_ELEMS];

    const int tile = (int)blockIdx.x;
    const int tid  = threadIdx.x;
    const size_t gbase = (size_t)tile * (KVBLK * Dq);

    unsigned short* kim = img + (size_t)tile * TILE_ELEMS;
    unsigned short* vtg = img + (size_t)(IMG_TILES + tile) * TILE_ELEMS;

    const float4* kt4 = (const float4*)(K + gbase);
    const float4* vt4 = (const float4*)(V + gbase);

    #pragma unroll
    for (int c = 0; c < 4; ++c) {
        const int r  = (c * 256 + tid) >> 4;     // row 0..63
        const int c0 = (tid & 15) * 4;           // col base
        {
            float4 u4 = kt4[c * 256 + tid];
            unsigned int p0 = f2bf(u4.x) | (f2bf(u4.y) << 16);   // RNE bf16
            unsigned int p1 = f2bf(u4.z) | (f2bf(u4.w) << 16);
            const int sw = c0 ^ (k_g(r) << 3);
            *(uint2*)(kim + r * 64 + sw) = make_uint2(p0, p1);
        }
        {
            float4 u4 = vt4[c * 256 + tid];
            float xs[4] = {u4.x, u4.y, u4.z, u4.w};
            #pragma unroll
            for (int e = 0; e < 4; ++e)
                VtL[vt_swz(c0 + e, r)] = (unsigned short)f2bf(xs[e]);
        }
    }
    __syncthreads();
    #pragma unroll
    for (int c = 0; c < 2; ++c)
        *(uint4*)(vtg + (c * 256 + tid) * 8) = *(const uint4*)(VtL + (c * 256 + tid) * 8);
}

// =====================================================================
// Main fp32-input MFMA flash attention (verified r13 structure):
// swapped QK^T (S^T = mfma(K,Q)) with permuted kv decomposition,
// in-register P via cvtpk, O^T accumulators, double-buffered staging.
// Round 14: conflict-free K image swizzle (per-lane-constant read XOR),
// hw exp2 builtin, tree-max.
// =====================================================================
__global__ __launch_bounds__(256, 3) void fa_mfma_f32_pre(
    const float* __restrict__ Q, const unsigned short* __restrict__ img,
    float* __restrict__ O, const int* __restrict__ flag)
{
    if (*flag) return;

    __shared__ __align__(16) unsigned short Kt[2][TILE_ELEMS];   // 16 KiB
    __shared__ __align__(16) unsigned short Vt[2][TILE_ELEMS];   // 16 KiB

    const int tid  = threadIdx.x;
    const int lane = tid & 63;
    const int w    = tid >> 6;       // wave 0..3
    const int l15  = lane & 15;
    const int lg   = lane >> 4;

    // XCD-aware bijective swizzle: 1024 blocks = 8 XCDs x 128
    const int bid  = (int)blockIdx.x;
    const int blk  = (bid & 7) * (NBLK_P / 8) + (bid >> 3);
    const int head = blk >> 4;               // 16 q-blocks per head
    const int q0   = (blk & 15) * QBLK_P;
    const size_t hb = (size_t)head * (Sq * Dq);

    // ---- Q fragments: 2 subtiles (m), scaled by 1/8*log2e, hi/lo split ----
    bf16x8 qh[2][2], ql[2][2];   // [m][s]
    #pragma unroll
    for (int m = 0; m < 2; ++m) {
        const float4* qv = (const float4*)(Q + hb
            + (size_t)(q0 + w * 32 + m * 16 + l15) * Dq + lg * 8);
        #pragma unroll
        for (int s = 0; s < 2; ++s) {
            float xs[8];
            #pragma unroll
            for (int j4 = 0; j4 < 2; ++j4) {
                float4 u = qv[s * 8 + j4];
                xs[j4*4+0]=u.x; xs[j4*4+1]=u.y; xs[j4*4+2]=u.z; xs[j4*4+3]=u.w;
            }
            #pragma unroll
            for (int j = 0; j < 8; ++j) {
                float x = xs[j] * QK_SCALE;
                unsigned int u = __float_as_uint(x);
                float hf = __uint_as_float(u & 0xffff0000u);
                qh[m][s][j] = (short)(u >> 16);
                ql[m][s][j] = (short)(__float_as_uint(x - hf) >> 16);
            }
        }
    }

    bf16x8 onesb;
    #pragma unroll
    for (int j = 0; j < 8; ++j) onesb[j] = (short)0x3F80;   // bf16 1.0

    // O^T accumulators: lane holds O[q=l15][d = dt*16 + lg*4 + r]
    f32x4 oacc0[4], oacc1[4];
    #pragma unroll
    for (int dt = 0; dt < 4; ++dt) {
        oacc0[dt] = (f32x4){0.f, 0.f, 0.f, 0.f};
        oacc1[dt] = (f32x4){0.f, 0.f, 0.f, 0.f};
    }
    f32x4 lacc0 = (f32x4){0.f,0.f,0.f,0.f}, lacc1 = (f32x4){0.f,0.f,0.f,0.f};
    float m0 = -1e30f, m1 = -1e30f;   // one scalar per lane: q is lane-local

    const unsigned short* kim_h = img + (size_t)(head * NKVIT) * TILE_ELEMS;
    const unsigned short* vtg_h = img + (size_t)(IMG_TILES + head * NKVIT) * TILE_ELEMS;

    // ---- async stage of tile T into LDS buffer B (4 x 16B per thread) ----
    #define STAGE(T, B)                                                 \
    {                                                                   \
        const size_t toff_ = (size_t)(T) * TILE_ELEMS;                  \
        _Pragma("unroll")                                               \
        for (int c_ = 0; c_ < 2; ++c_) {                                \
            const int e8_ = (c_ * 256 + tid) * 8;                       \
            gload_lds16(kim_h + toff_ + e8_, &Kt[B][e8_]);              \
            gload_lds16(vtg_h + toff_ + e8_, &Vt[B][e8_]);              \
        }                                                               \
    }

    STAGE(0, 0)

    // permuted K A-frag row base and per-lane-constant granule XOR
    const int krb  = ((l15 >> 2) << 3) + (l15 & 3);
    const int kxor = ((l15 & 3) | (((l15 >> 2) & 1) << 2)) << 3;   // = k_g(krow)<<3

    for (int it = 0; it < NKVIT; ++it) {
        const int cur = it & 1;
        asm volatile("s_waitcnt vmcnt(0)" ::: "memory");
        __syncthreads();   // all waves staged buf[cur] + finished reading buf[cur^1]
        if (it + 1 < NKVIT) STAGE(it + 1, cur ^ 1)

        const unsigned short* KtC = &Kt[cur][0];
        const unsigned short* VtC = &Vt[cur][0];

        // ---- swapped QK^T: s[nt][r] = S[q=l15][kv=(nt&1)*32+lg*8+(nt>>1)*4+r]
        f32x4 s0[4], s1[4];
        #pragma unroll
        for (int nt = 0; nt < 4; ++nt) {
            s0[nt] = (f32x4){0.f,0.f,0.f,0.f};
            s1[nt] = (f32x4){0.f,0.f,0.f,0.f};
        }
        __builtin_amdgcn_s_setprio(1);
        #pragma unroll
        for (int s = 0; s < 2; ++s) {
            #pragma unroll
            for (int nt = 0; nt < 4; ++nt) {
                const int krow = ((nt & 1) << 5) + ((nt >> 1) << 2) + krb;
                const int off  = krow * 64 + ((s * 32 + lg * 8) ^ kxor);
                bf16x8 kf = *(const bf16x8*)(KtC + off);
                s0[nt] = __builtin_amdgcn_mfma_f32_16x16x32_bf16(kf, qh[0][s], s0[nt], 0, 0, 0);
                s0[nt] = __builtin_amdgcn_mfma_f32_16x16x32_bf16(kf, ql[0][s], s0[nt], 0, 0, 0);
                s1[nt] = __builtin_amdgcn_mfma_f32_16x16x32_bf16(kf, qh[1][s], s1[nt], 0, 0, 0);
                s1[nt] = __builtin_amdgcn_mfma_f32_16x16x32_bf16(kf, ql[1][s], s1[nt], 0, 0, 0);
            }
        }
        __builtin_amdgcn_s_setprio(0);

        // ---- softmax: q lane-local; tree max; full reduce only on grow ----
        float a00 = fmaxf(fmaxf(s0[0][0], s0[0][1]), fmaxf(s0[0][2], s0[0][3]));
        float a01 = fmaxf(fmaxf(s0[1][0], s0[1][1]), fmaxf(s0[1][2], s0[1][3]));
        float a02 = fmaxf(fmaxf(s0[2][0], s0[2][1]), fmaxf(s0[2][2], s0[2][3]));
        float a03 = fmaxf(fmaxf(s0[3][0], s0[3][1]), fmaxf(s0[3][2], s0[3][3]));
        float lm0 = fmaxf(fmaxf(a00, a01), fmaxf(a02, a03));
        float a10 = fmaxf(fmaxf(s1[0][0], s1[0][1]), fmaxf(s1[0][2], s1[0][3]));
        float a11 = fmaxf(fmaxf(s1[1][0], s1[1][1]), fmaxf(s1[1][2], s1[1][3]));
        float a12 = fmaxf(fmaxf(s1[2][0], s1[2][1]), fmaxf(s1[2][2], s1[2][3]));
        float a13 = fmaxf(fmaxf(s1[3][0], s1[3][1]), fmaxf(s1[3][2], s1[3][3]));
        float lm1 = fmaxf(fmaxf(a10, a11), fmaxf(a12, a13));

        if (__any((lm0 > m0 + DEFER_THR) | (lm1 > m1 + DEFER_THR))) {
            float t0 = lm0, t1 = lm1;
            t0 = fmaxf(t0, __shfl_xor(t0, 16, 64));
            t0 = fmaxf(t0, __shfl_xor(t0, 32, 64));
            t1 = fmaxf(t1, __shfl_xor(t1, 16, 64));
            t1 = fmaxf(t1, __shfl_xor(t1, 32, 64));
            float n0 = fmaxf(m0, t0), n1 = fmaxf(m1, t1);
            float b0 = __builtin_amdgcn_exp2f(m0 - n0);
            float b1 = __builtin_amdgcn_exp2f(m1 - n1);
            m0 = n0; m1 = n1;
            #pragma unroll
            for (int dt = 0; dt < 4; ++dt) { oacc0[dt] *= b0; oacc1[dt] *= b1; }
            lacc0 *= b0; lacc1 *= b1;
        }
        #pragma unroll
        for (int nt = 0; nt < 4; ++nt) {
            #pragma unroll
            for (int r = 0; r < 4; ++r) {
                s0[nt][r] = __builtin_amdgcn_exp2f(s0[nt][r] - m0);   // <= 2^8
                s1[nt][r] = __builtin_amdgcn_exp2f(s1[nt][r] - m1);
            }
        }

        // ---- in-register P pack + PV + lsum ----
        // p[j] = P[q=l15][kv=s2*32+lg*8+j] = s[s2+2*(j>>2)][j&3]
        #pragma unroll
        for (int s2 = 0; s2 < 2; ++s2) {
            union { unsigned int u[4]; bf16x8 v; } p0, p1;
            p0.u[0] = cvtpk(s0[s2    ][0], s0[s2    ][1]);
            p0.u[1] = cvtpk(s0[s2    ][2], s0[s2    ][3]);
            p0.u[2] = cvtpk(s0[s2 + 2][0], s0[s2 + 2][1]);
            p0.u[3] = cvtpk(s0[s2 + 2][2], s0[s2 + 2][3]);
            p1.u[0] = cvtpk(s1[s2    ][0], s1[s2    ][1]);
            p1.u[1] = cvtpk(s1[s2    ][2], s1[s2    ][3]);
            p1.u[2] = cvtpk(s1[s2 + 2][0], s1[s2 + 2][1]);
            p1.u[3] = cvtpk(s1[s2 + 2][2], s1[s2 + 2][3]);
            __builtin_amdgcn_s_setprio(1);
            lacc0 = __builtin_amdgcn_mfma_f32_16x16x32_bf16(onesb, p0.v, lacc0, 0, 0, 0);
            lacc1 = __builtin_amdgcn_mfma_f32_16x16x32_bf16(onesb, p1.v, lacc1, 0, 0, 0);
            #pragma unroll
            for (int dt = 0; dt < 4; ++dt) {
                bf16x8 vf = *(const bf16x8*)(VtC + vt_swz(dt * 16 + l15, s2 * 32 + lg * 8));
                oacc0[dt] = __builtin_amdgcn_mfma_f32_16x16x32_bf16(vf, p0.v, oacc0[dt], 0, 0, 0);
                oacc1[dt] = __builtin_amdgcn_mfma_f32_16x16x32_bf16(vf, p1.v, oacc1[dt], 0, 0, 0);
            }
            __builtin_amdgcn_s_setprio(0);
        }
    }
    #undef STAGE

    // ---- epilogue: O^T layout -> float4 per d-quad ----
    {
        const float inv = 1.f / lacc0[0];
        float* ob = O + hb + (size_t)(q0 + w * 32 + l15) * Dq;
        #pragma unroll
        for (int dt = 0; dt < 4; ++dt) {
            float4 v; v.x = oacc0[dt][0] * inv; v.y = oacc0[dt][1] * inv;
                      v.z = oacc0[dt][2] * inv; v.w = oacc0[dt][3] * inv;
            *(float4*)(ob + dt * 16 + lg * 4) = v;
        }
    }
    {
        const float inv = 1.f / lacc1[0];
        float* ob = O + hb + (size_t)(q0 + w * 32 + 16 + l15) * Dq;
        #pragma unroll
        for (int dt = 0; dt < 4; ++dt) {
            float4 v; v.x = oacc1[dt][0] * inv; v.y = oacc1[dt][1] * inv;
                      v.z = oacc1[dt][2] * inv; v.w = oacc1[dt][3] * inv;
            *(float4*)(ob + dt * 16 + lg * 4) = v;
        }
    }
}

// =====================================================================
// Fallback fused fp32 kernel (used when ws too small) — round-3 version
// =====================================================================
__global__ __launch_bounds__(256, 2) void fa_mfma_f32_fused(
    const float* __restrict__ Q, const float* __restrict__ K,
    const float* __restrict__ V, float* __restrict__ O,
    const int* __restrict__ flag)
{
    if (*flag) return;

    __shared__ __align__(16) unsigned short Kh[KVBLK * Dq];
    __shared__ __align__(16) unsigned short Kl[KVBLK * Dq];
    __shared__ __align__(16) unsigned short Vt[Dq * KVBLK];
    __shared__ __align__(16) unsigned short Pl[4][16 * PT_STRIDE];

    const int tid  = threadIdx.x;
    const int lane = tid & 63;
    const int w    = tid >> 6;
    const int l15  = lane & 15;
    const int lg   = lane >> 4;

    const int bid  = (int)blockIdx.x;
    const int blk  = (bid & 7) * (NBLK / 8) + (bid >> 3);
    const int head = blk >> 5;
    const int q0   = (blk & 31) * QBLK;
    const size_t hb = (size_t)head * (Sq * Dq);

    bf16x8 qh[2], ql[2];
    {
        const float* qp = Q + hb + (size_t)(q0 + w * 16 + l15) * Dq + lg * 8;
        #pragma unroll
        for (int s = 0; s < 2; ++s) {
            #pragma unroll
            for (int j = 0; j < 8; ++j) {
                float x = qp[s * 32 + j] * 0.125f;
                unsigned int u = __float_as_uint(x);
                float hf = __uint_as_float(u & 0xffff0000u);
                qh[s][j] = (short)(u >> 16);
                ql[s][j] = (short)(__float_as_uint(x - hf) >> 16);
            }
        }
    }

    f32x4 oacc[4];
    #pragma unroll
    for (int dt = 0; dt < 4; ++dt) oacc[dt] = (f32x4){0.f, 0.f, 0.f, 0.f};
    float mrow[4], lrow[4];
    #pragma unroll
    for (int r = 0; r < 4; ++r) { mrow[r] = -1e30f; lrow[r] = 0.f; }

    const float* kbase = K + hb;
    const float* vbase = V + hb;

    float4 kr[4], vr[4];
    {
        const float4* kt4 = (const float4*)kbase;
        const float4* vt4 = (const float4*)vbase;
        #pragma unroll
        for (int c = 0; c < 4; ++c) { kr[c] = kt4[c * 256 + tid]; vr[c] = vt4[c * 256 + tid]; }
    }

    for (int it = 0; it < NKVIT; ++it) {
        __syncthreads();
        #pragma unroll
        for (int c = 0; c < 4; ++c) {
            const int r  = c * 16 + (tid >> 4);
            const int c0 = (tid & 15) * 4;
            const int sw = c0 ^ ((r & 7) << 3);
            float xs[4] = {kr[c].x, kr[c].y, kr[c].z, kr[c].w};
            unsigned int hp[2], lp[2];
            #pragma unroll
            for (int e = 0; e < 2; ++e) {
                unsigned int u0 = __float_as_uint(xs[2*e]);
                unsigned int u1 = __float_as_uint(xs[2*e+1]);
                hp[e] = (u0 >> 16) | (u1 & 0xffff0000u);
                float h0 = __uint_as_float(u0 & 0xffff0000u);
                float h1 = __uint_as_float(u1 & 0xffff0000u);
                lp[e] = (__float_as_uint(xs[2*e] - h0) >> 16)
                      | (__float_as_uint(xs[2*e+1] - h1) & 0xffff0000u);
            }
            *(uint2*)(Kh + r * 64 + sw) = make_uint2(hp[0], hp[1]);
            *(uint2*)(Kl + r * 64 + sw) = make_uint2(lp[0], lp[1]);
        }
        #pragma unroll
        for (int c = 0; c < 4; ++c) {
            const int kv = c * 16 + (tid >> 4);
            const int d0 = (tid & 15) * 4;
            float xs[4] = {vr[c].x, vr[c].y, vr[c].z, vr[c].w};
            #pragma unroll
            for (int e = 0; e < 4; ++e)
                Vt[vt_swz(d0 + e, kv)] = (unsigned short)f2bf(xs[e]);
        }
        __syncthreads();

        if (it + 1 < NKVIT) {
            const float4* kt4 = (const float4*)(kbase + (size_t)(it + 1) * KVBLK * Dq);
            const float4* vt4 = (const float4*)(vbase + (size_t)(it + 1) * KVBLK * Dq);
            #pragma unroll
            for (int c = 0; c < 4; ++c) { kr[c] = kt4[c * 256 + tid]; vr[c] = vt4[c * 256 + tid]; }
        }

        f32x4 sacc[4];
        #pragma unroll
        for (int nt = 0; nt < 4; ++nt) sacc[nt] = (f32x4){0.f, 0.f, 0.f, 0.f};
        #pragma unroll
        for (int s = 0; s < 2; ++s) {
            #pragma unroll
            for (int nt = 0; nt < 4; ++nt) {
                const int n = nt * 16 + l15;
                const int off = n * 64 + ((s * 32 + lg * 8) ^ ((n & 7) << 3));
                bf16x8 khf = *(const bf16x8*)(Kh + off);
                bf16x8 klf = *(const bf16x8*)(Kl + off);
                sacc[nt] = __builtin_amdgcn_mfma_f32_16x16x32_bf16(qh[s], khf, sacc[nt], 0, 0, 0);
                sacc[nt] = __builtin_amdgcn_mfma_f32_16x16x32_bf16(qh[s], klf, sacc[nt], 0, 0, 0);
                sacc[nt] = __builtin_amdgcn_mfma_f32_16x16x32_bf16(ql[s], khf, sacc[nt], 0, 0, 0);
            }
        }

        float mnew[4], alpha[4];
        #pragma unroll
        for (int r = 0; r < 4; ++r) {
            float t = fmaxf(fmaxf(sacc[0][r], sacc[1][r]), fmaxf(sacc[2][r], sacc[3][r]));
            #pragma unroll
            for (int msk = 1; msk <= 8; msk <<= 1)
                t = fmaxf(t, __shfl_xor(t, msk, 64));
            mnew[r]  = fmaxf(mrow[r], t);
            alpha[r] = __expf(mrow[r] - mnew[r]);
            mrow[r]  = mnew[r];
        }
        float psum[4] = {0.f, 0.f, 0.f, 0.f};
        #pragma unroll
        for (int nt = 0; nt < 4; ++nt) {
            #pragma unroll
            for (int r = 0; r < 4; ++r) {
                float p = __expf(sacc[nt][r] - mnew[r]);
                sacc[nt][r] = p;
                psum[r] += p;
            }
        }
        #pragma unroll
        for (int r = 0; r < 4; ++r) {
            float t = psum[r];
            #pragma unroll
            for (int msk = 1; msk <= 8; msk <<= 1)
                t += __shfl_xor(t, msk, 64);
            lrow[r] = lrow[r] * alpha[r] + t;
        }
        {
            f32x4 av; av[0] = alpha[0]; av[1] = alpha[1]; av[2] = alpha[2]; av[3] = alpha[3];
            #pragma unroll
            for (int dt = 0; dt < 4; ++dt) oacc[dt] *= av;
        }

        unsigned short* pw = &Pl[w][0];
        #pragma unroll
        for (int nt = 0; nt < 4; ++nt) {
            const int cc = nt * 16 + l15;
            #pragma unroll
            for (int r = 0; r < 4; ++r)
                pw[(lg * 4 + r) * PT_STRIDE + cc] = (unsigned short)f2bf(sacc[nt][r]);
        }

        #pragma unroll
        for (int s2 = 0; s2 < 2; ++s2) {
            bf16x8 pf = *(const bf16x8*)(pw + l15 * PT_STRIDE + s2 * 32 + lg * 8);
            #pragma unroll
            for (int dt = 0; dt < 4; ++dt) {
                const int d = dt * 16 + l15;
                bf16x8 vf = *(const bf16x8*)(Vt + vt_swz(d, s2 * 32 + lg * 8));
                oacc[dt] = __builtin_amdgcn_mfma_f32_16x16x32_bf16(pf, vf, oacc[dt], 0, 0, 0);
            }
        }
    }

    float inv4[4];
    #pragma unroll
    for (int r = 0; r < 4; ++r) inv4[r] = 1.f / lrow[r];
    float* ob = O + hb + (size_t)(q0 + w * 16) * Dq;
    #pragma unroll
    for (int dt = 0; dt < 4; ++dt) {
        #pragma unroll
        for (int r = 0; r < 4; ++r)
            ob[(size_t)(lg * 4 + r) * Dq + dt * 16 + l15] = oacc[dt][r] * inv4[r];
    }
}

// =====================================================================
// bf16-input MFMA flash attention (flag=1 robustness; unchanged)
// =====================================================================
__global__ __launch_bounds__(256, 3) void fa_mfma_bf16(
    const unsigned short* __restrict__ Q, const unsigned short* __restrict__ K,
    const unsigned short* __restrict__ V, unsigned short* __restrict__ O,
    const int* __restrict__ flag)
{
    if (!(*flag)) return;

    __shared__ __align__(16) unsigned short Kt[KVBLK * Dq];
    __shared__ __align__(16) unsigned short Vt[Dq * KVBLK];
    __shared__ __align__(16) unsigned short Pl[4][16 * PT_STRIDE];

    const int tid  = threadIdx.x;
    const int lane = tid & 63;
    const int w    = tid >> 6;
    const int l15  = lane & 15;
    const int lg   = lane >> 4;

    const int bid  = (int)blockIdx.x;
    const int blk  = (bid & 7) * (NBLK / 8) + (bid >> 3);
    const int head = blk >> 5;
    const int q0   = (blk & 31) * QBLK;
    const size_t hb = (size_t)head * (Sq * Dq);

    bf16x8 qf[2];
    {
        const bf16x8* qp = (const bf16x8*)(Q + hb + (size_t)(q0 + w * 16 + l15) * Dq);
        qf[0] = qp[lg];
        qf[1] = qp[4 + lg];
    }

    f32x4 oacc[4];
    #pragma unroll
    for (int dt = 0; dt < 4; ++dt) oacc[dt] = (f32x4){0.f, 0.f, 0.f, 0.f};
    float mrow[4], lrow[4];
    #pragma unroll
    for (int r = 0; r < 4; ++r) { mrow[r] = -1e30f; lrow[r] = 0.f; }

    const int sr = tid >> 3;
    const int sc = tid & 7;
    const int kswz_elem = (sc * 8) ^ ((sr & 7) << 3);

    for (int it = 0; it < NKVIT; ++it) {
        const int kv0 = it * KVBLK;
        __syncthreads();
        #pragma unroll
        for (int c = 0; c < 2; ++c) {
            gload_lds16(K + hb + (size_t)(kv0 + c * 32 + sr) * Dq + kswz_elem,
                        Kt + c * 2048 + tid * 8);
        }
        uint4 vreg[2];
        #pragma unroll
        for (int c = 0; c < 2; ++c)
            vreg[c] = *(const uint4*)(V + hb + (size_t)(kv0 + c * 32 + sr) * Dq + sc * 8);

        asm volatile("s_waitcnt vmcnt(0)" ::: "memory");

        #pragma unroll
        for (int c = 0; c < 2; ++c) {
            const int kv = c * 32 + sr;
            unsigned int vu[4] = { vreg[c].x, vreg[c].y, vreg[c].z, vreg[c].w };
            #pragma unroll
            for (int e2 = 0; e2 < 4; ++e2) {
                const int d0 = sc * 8 + e2 * 2;
                Vt[vt_swz(d0,     kv)] = (unsigned short)(vu[e2] & 0xffffu);
                Vt[vt_swz(d0 + 1, kv)] = (unsigned short)(vu[e2] >> 16);
            }
        }
        __syncthreads();

        f32x4 sacc[4];
        #pragma unroll
        for (int nt = 0; nt < 4; ++nt) sacc[nt] = (f32x4){0.f, 0.f, 0.f, 0.f};
        #pragma unroll
        for (int s = 0; s < 2; ++s) {
            #pragma unroll
            for (int nt = 0; nt < 4; ++nt) {
                const int n = nt * 16 + l15;
                bf16x8 kf = *(const bf16x8*)(Kt + n * 64 + ((s * 32 + lg * 8) ^ ((n & 7) << 3)));
                sacc[nt] = __builtin_amdgcn_mfma_f32_16x16x32_bf16(qf[s], kf, sacc[nt], 0, 0, 0);
            }
        }
        #pragma unroll
        for (int nt = 0; nt < 4; ++nt) sacc[nt] *= 0.125f;

        float mnew[4], alpha[4];
        #pragma unroll
        for (int r = 0; r < 4; ++r) {
            float t = fmaxf(fmaxf(sacc[0][r], sacc[1][r]), fmaxf(sacc[2][r], sacc[3][r]));
            #pragma unroll
            for (int msk = 1; msk <= 8; msk <<= 1)
                t = fmaxf(t, __shfl_xor(t, msk, 64));
            mnew[r]  = fmaxf(mrow[r], t);
            alpha[r] = __expf(mrow[r] - mnew[r]);
            mrow[r]  = mnew[r];
        }
        float psum[4] = {0.f, 0.f, 0.f, 0.f};
        #pragma unroll
        for (int nt = 0; nt < 4; ++nt) {
            #pragma unroll
            for (int r = 0; r < 4; ++r) {
                float p = __expf(sacc[nt][r] - mnew[r]);
                sacc[nt][r] = p;
                psum[r] += p;
            }
        }
        #pragma unroll
        for (int r = 0; r < 4; ++r) {
            float t = psum[r];
            #pragma unroll
            for (int msk = 1; msk <= 8; msk <<= 1)
                t += __shfl_xor(t, msk, 64);
            lrow[r] = lrow[r] * alpha[r] + t;
        }
        {
            f32x4 av; av[0] = alpha[0]; av[1] = alpha[1]; av[2] = alpha[2]; av[3] = alpha[3];
            #pragma unroll
            for (int dt = 0; dt < 4; ++dt) oacc[dt] *= av;
        }

        unsigned short* pw = &Pl[w][0];
        #pragma unroll
        for (int nt = 0; nt < 4; ++nt) {
            const int cc = nt * 16 + l15;
            #pragma unroll
            for (int r = 0; r < 4; ++r)
                pw[(lg * 4 + r) * PT_STRIDE + cc] = (unsigned short)f2bf(sacc[nt][r]);
        }

        #pragma unroll
        for (int s2 = 0; s2 < 2; ++s2) {
            bf16x8 pf = *(const bf16x8*)(pw + l15 * PT_STRIDE + s2 * 32 + lg * 8);
            #pragma unroll
            for (int dt = 0; dt < 4; ++dt) {
                const int d = dt * 16 + l15;
                bf16x8 vf = *(const bf16x8*)(Vt + vt_swz(d, s2 * 32 + lg * 8));
                oacc[dt] = __builtin_amdgcn_mfma_f32_16x16x32_bf16(pf, vf, oacc[dt], 0, 0, 0);
            }
        }
    }

    float inv4[4];
    #pragma unroll
    for (int r = 0; r < 4; ++r) inv4[r] = 1.f / lrow[r];
    unsigned short* ob = O + (size_t)(head * Sq + q0 + w * 16) * Dq;
    #pragma unroll
    for (int dt = 0; dt < 4; ++dt) {
        #pragma unroll
        for (int r = 0; r < 4; ++r)
            ob[(size_t)(lg * 4 + r) * Dq + dt * 16 + l15] = (unsigned short)f2bf(oacc[dt][r] * inv4[r]);
    }
}

extern "C" void kernel_launch(void* const* d_in, const int* in_sizes, int n_in,
                              void* d_out, int out_size, void* d_ws, size_t ws_size,
                              hipStream_t stream) {
    int* flag = (int*)d_ws;
    detect_dtype<<<dim3(1), dim3(64), 0, stream>>>((const unsigned int*)d_in[0], flag);
    if (ws_size >= WS_NEEDED) {
        unsigned short* img = (unsigned short*)((char*)d_ws + WS_IMG_OFF);
        convert_kv<<<dim3(IMG_TILES), dim3(256), 0, stream>>>(
            (const float*)d_in[1], (const float*)d_in[2], img, flag);
        fa_mfma_f32_pre<<<dim3(NBLK_P), dim3(256), 0, stream>>>(
            (const float*)d_in[0], img, (float*)d_out, flag);
    } else {
        fa_mfma_f32_fused<<<dim3(NBLK), dim3(256), 0, stream>>>(
            (const float*)d_in[0], (const float*)d_in[1],
            (const float*)d_in[2], (float*)d_out, flag);
    }
    fa_mfma_bf16<<<dim3(NBLK), dim3(256), 0, stream>>>(
        (const unsigned short*)d_in[0], (const unsigned short*)d_in[1],
        (const unsigned short*)d_in[2], (unsigned short*)d_out, flag);
}